// Round 3
// baseline (537.246 us; speedup 1.0000x reference)
//
#include <hip/hip_runtime.h>
#include <hip/hip_bf16.h>

#define EPSV 1e-5f
#define BM   64
#define XSTR 296   // unified row stride (bf16): 592 B = 16B-aligned; also f32 delta stride 148
#define DSTR 148   // delta row stride (f32) == XSTR*2 bytes

using bf16x8 = __attribute__((ext_vector_type(8))) short;
using f32x4  = __attribute__((ext_vector_type(4))) float;
using us8    = __attribute__((ext_vector_type(8))) unsigned short;

__device__ __forceinline__ unsigned short f2bf(float f) {
    unsigned int u = __float_as_uint(f);
    u += 0x7fffu + ((u >> 16) & 1u);   // RNE
    return (unsigned short)(u >> 16);
}

// ---------------- weight prep ----------------
// Fragment storage: ((s*NT + t)*64 + lane)*8 + i  holds  W[k = 32*s + 8*(lane>>4) + i][n = 16*t + (lane&15)]
// Packed-K order for W0: [logits 0..15 | hidden 16..143 | msg 144..287 | layer_pe 288..415 | intra 416..543]
//   orig row = k<144 ? k : (k<288 ? k+257 : k-144);  row 400 (loss) folded into b0_eff.
__global__ void prep_kernel(const float* __restrict__ W0, const float* __restrict__ b0,
                            const float* __restrict__ ln_loss_b,
                            const float* __restrict__ W1, const float* __restrict__ W2,
                            unsigned short* __restrict__ W0p, unsigned short* __restrict__ W1p,
                            unsigned short* __restrict__ W2p, float* __restrict__ b0e)
{
    int gtid = blockIdx.x * blockDim.x + threadIdx.x;
    if (gtid < 17408) {                       // W0p: 17 ksteps x 16 ntiles
        int lane = gtid & 63, fid = gtid >> 6;
        int s = fid >> 4, t = fid & 15;
        int n  = (t << 4) + (lane & 15);
        int kb = (s << 5) + ((lane >> 4) << 3);
        us8 v;
        #pragma unroll
        for (int i = 0; i < 8; ++i) {
            int k = kb + i;
            int orig = (k < 144) ? k : ((k < 288) ? (k + 257) : (k - 144));
            v[i] = f2bf(W0[orig * 256 + n]);
        }
        *reinterpret_cast<us8*>(W0p + gtid * 8) = v;
    } else if (gtid < 17408 + 8192) {         // W1p: 8 x 16
        int g = gtid - 17408;
        int lane = g & 63, fid = g >> 6;
        int s = fid >> 4, t = fid & 15;
        int n  = (t << 4) + (lane & 15);
        int kb = (s << 5) + ((lane >> 4) << 3);
        us8 v;
        #pragma unroll
        for (int i = 0; i < 8; ++i) v[i] = f2bf(W1[(kb + i) * 256 + n]);
        *reinterpret_cast<us8*>(W1p + g * 8) = v;
    } else if (gtid < 17408 + 8192 + 4608) {  // W2p: 8 x 9
        int g = gtid - 17408 - 8192;
        int lane = g & 63, fid = g >> 6;
        int s = fid / 9, t = fid % 9;
        int n  = (t << 4) + (lane & 15);
        int kb = (s << 5) + ((lane >> 4) << 3);
        us8 v;
        #pragma unroll
        for (int i = 0; i < 8; ++i) v[i] = f2bf(W2[(kb + i) * 144 + n]);
        *reinterpret_cast<us8*>(W2p + g * 8) = v;
    } else if (gtid < 17408 + 8192 + 4608 + 256) {
        int n = gtid - (17408 + 8192 + 4608);
        b0e[n] = b0[n] + ln_loss_b[0] * W0[400 * 256 + n];
    }
}

// ---------------- input LN staging: 8 threads per row, 32 rows per pass ----------------
// Lane-contiguous element map: element e = 2*sub + 16*j  (sub = tid&7, j = float2 idx)
// -> for fixed j, 8 lanes cover 64 contiguous bytes; rows of a wave cover 8 rows.
// Peak live regs: NV float2 = max 18 (msg) -> no spill pressure while acc is live.
template<int L>
__device__ __forceinline__ void stage8(
    const float* __restrict__ src,
    const float* __restrict__ sc, const float* __restrict__ bi,
    unsigned short* xb, int dstcol, int tid, int row0, int rbase)
{
    constexpr int NV = L / 16;                 // float2 per thread (16->1, 128->8, 144->9)
    const int sub = tid & 7;
    const int r   = (tid >> 3) + rbase;        // rbase in {0, 32}
    const float* p = src + (size_t)(row0 + r) * L + 2 * sub;
    float2 v[NV];
    float ps = 0.f, pq = 0.f;
    #pragma unroll
    for (int j = 0; j < NV; ++j) {
        v[j] = *reinterpret_cast<const float2*>(p + 16 * j);
        ps += v[j].x + v[j].y;
        pq += v[j].x * v[j].x + v[j].y * v[j].y;
    }
    ps += __shfl_xor(ps, 1); ps += __shfl_xor(ps, 2); ps += __shfl_xor(ps, 4);
    pq += __shfl_xor(pq, 1); pq += __shfl_xor(pq, 2); pq += __shfl_xor(pq, 4);
    const float mu   = ps * (1.f / L);
    const float rstd = rsqrtf(pq * (1.f / L) - mu * mu + EPSV);
    unsigned short* dst = xb + r * XSTR + dstcol + 2 * sub;
    const float* scp = sc + 2 * sub;
    const float* bip = bi + 2 * sub;
    #pragma unroll
    for (int j = 0; j < NV; ++j) {
        float2 sv = *reinterpret_cast<const float2*>(scp + 16 * j);
        float2 bv = *reinterpret_cast<const float2*>(bip + 16 * j);
        unsigned int pk = (unsigned int)f2bf((v[j].x - mu) * rstd * sv.x + bv.x)
                        | ((unsigned int)f2bf((v[j].y - mu) * rstd * sv.y + bv.y) << 16);
        *reinterpret_cast<unsigned int*>(dst + 16 * j) = pk;
    }
}

// ---------------- fused main kernel ----------------
// Single LDS buffer lifecycle (all transitions barrier-separated):
//   x chunk1 (288 cols) -> x chunk2 (256 cols) -> h0 (256) -> h1 (256) -> delta f32 (144)
__global__ __launch_bounds__(256, 4) void node_update_kernel(
    const float* __restrict__ logits, const float* __restrict__ hidden,
    const float* __restrict__ layer_pe, const float* __restrict__ intra,
    const int* __restrict__ layer, const float* __restrict__ msg,
    const float* __restrict__ ln_logits_s, const float* __restrict__ ln_logits_b,
    const float* __restrict__ ln_hidden_s, const float* __restrict__ ln_hidden_b,
    const float* __restrict__ ln_layer_pe_s, const float* __restrict__ ln_layer_pe_b,
    const float* __restrict__ ln_intra_pe_s, const float* __restrict__ ln_intra_pe_b,
    const float* __restrict__ ln_msg_s, const float* __restrict__ ln_msg_b,
    const unsigned short* __restrict__ W0p, const float* __restrict__ b0e,
    const float* __restrict__ mlp_ln0_s, const float* __restrict__ mlp_ln0_b,
    const unsigned short* __restrict__ W1p, const float* __restrict__ b1,
    const float* __restrict__ mlp_ln1_s, const float* __restrict__ mlp_ln1_b,
    const unsigned short* __restrict__ W2p, const float* __restrict__ b2,
    float* __restrict__ out)
{
    __shared__ __align__(16) unsigned short sbuf[BM * XSTR];  // 37888 B, multi-purpose
    __shared__ __align__(16) float redf[BM * 4 * 2];          // 2048 B
    __shared__ int lyr[BM];

    float2* redp = reinterpret_cast<float2*>(redf);
    const int tid  = threadIdx.x;
    const int lane = tid & 63;
    const int w    = tid >> 6;
    const int l15  = lane & 15;
    const int lg   = lane >> 4;
    const int row0 = blockIdx.x * BM;

    // ---- phase A: stage chunk1 (logits|hidden|msg = 288 cols) ----
    #pragma unroll 1
    for (int rb = 0; rb < 2; ++rb) {
        stage8<16 >(logits, ln_logits_s, ln_logits_b, sbuf,   0, tid, row0, rb * 32);
        stage8<128>(hidden, ln_hidden_s, ln_hidden_b, sbuf,  16, tid, row0, rb * 32);
        stage8<144>(msg,    ln_msg_s,    ln_msg_b,    sbuf, 144, tid, row0, rb * 32);
    }
    if (tid < BM) lyr[tid] = layer[row0 + tid];
    __syncthreads();

    // ---- GEMM1 (K=544), wave w owns output cols 64w..64w+63 ----
    f32x4 acc[4][4];
    #pragma unroll
    for (int m = 0; m < 4; ++m)
        #pragma unroll
        for (int t = 0; t < 4; ++t)
            acc[m][t] = (f32x4){0.f, 0.f, 0.f, 0.f};

    for (int s = 0; s < 9; ++s) {             // chunk1: k 0..287
        bf16x8 a[4];
        #pragma unroll
        for (int m = 0; m < 4; ++m)
            a[m] = *reinterpret_cast<const bf16x8*>(&sbuf[(16 * m + l15) * XSTR + 32 * s + 8 * lg]);
        #pragma unroll
        for (int t = 0; t < 4; ++t) {
            bf16x8 b = *reinterpret_cast<const bf16x8*>(W0p + (((s * 16 + w * 4 + t) * 64 + lane) << 3));
            #pragma unroll
            for (int m = 0; m < 4; ++m)
                acc[m][t] = __builtin_amdgcn_mfma_f32_16x16x32_bf16(a[m], b, acc[m][t], 0, 0, 0);
        }
    }
    __syncthreads();
    // ---- phase B: stage chunk2 (layer_pe|intra = 256 cols); acc is live -> lean staging ----
    #pragma unroll 1
    for (int rb = 0; rb < 2; ++rb) {
        stage8<128>(layer_pe, ln_layer_pe_s, ln_layer_pe_b, sbuf,   0, tid, row0, rb * 32);
        stage8<128>(intra,    ln_intra_pe_s, ln_intra_pe_b, sbuf, 128, tid, row0, rb * 32);
    }
    __syncthreads();
    for (int s = 0; s < 8; ++s) {             // chunk2: k 288..543 (global kstep s+9)
        bf16x8 a[4];
        #pragma unroll
        for (int m = 0; m < 4; ++m)
            a[m] = *reinterpret_cast<const bf16x8*>(&sbuf[(16 * m + l15) * XSTR + 32 * s + 8 * lg]);
        #pragma unroll
        for (int t = 0; t < 4; ++t) {
            bf16x8 b = *reinterpret_cast<const bf16x8*>(W0p + ((((s + 9) * 16 + w * 4 + t) * 64 + lane) << 3));
            #pragma unroll
            for (int m = 0; m < 4; ++m)
                acc[m][t] = __builtin_amdgcn_mfma_f32_16x16x32_bf16(a[m], b, acc[m][t], 0, 0, 0);
        }
    }

    // ---- LN0 + ReLU -> h0 (bf16, overwrites x in sbuf after barrier) ----
    {
        float bv[4], sv[4], bb[4];
        #pragma unroll
        for (int t = 0; t < 4; ++t) {
            int n = w * 64 + t * 16 + l15;
            bv[t] = b0e[n]; sv[t] = mlp_ln0_s[n]; bb[t] = mlp_ln0_b[n];
        }
        #pragma unroll
        for (int m = 0; m < 4; ++m)
            #pragma unroll
            for (int t = 0; t < 4; ++t)
                #pragma unroll
                for (int i = 0; i < 4; ++i)
                    acc[m][t][i] += bv[t];
        #pragma unroll
        for (int m = 0; m < 4; ++m) {
            #pragma unroll
            for (int i = 0; i < 4; ++i) {
                float ps = acc[m][0][i] + acc[m][1][i] + acc[m][2][i] + acc[m][3][i];
                float pq = acc[m][0][i] * acc[m][0][i] + acc[m][1][i] * acc[m][1][i]
                         + acc[m][2][i] * acc[m][2][i] + acc[m][3][i] * acc[m][3][i];
                ps += __shfl_xor(ps, 1); ps += __shfl_xor(ps, 2); ps += __shfl_xor(ps, 4); ps += __shfl_xor(ps, 8);
                pq += __shfl_xor(pq, 1); pq += __shfl_xor(pq, 2); pq += __shfl_xor(pq, 4); pq += __shfl_xor(pq, 8);
                if (l15 == 0) redp[(16 * m + 4 * lg + i) * 4 + w] = make_float2(ps, pq);
            }
        }
        __syncthreads();   // also guarantees all GEMM1-chunk2 LDS reads are done
        if (tid < BM) {
            float2 a0 = redp[tid * 4 + 0], a1 = redp[tid * 4 + 1], a2 = redp[tid * 4 + 2], a3 = redp[tid * 4 + 3];
            float s  = a0.x + a1.x + a2.x + a3.x;
            float q  = a0.y + a1.y + a2.y + a3.y;
            float mu = s * (1.f / 256.f);
            float rstd = rsqrtf(q * (1.f / 256.f) - mu * mu + EPSV);
            redp[tid * 4 + 0] = make_float2(mu, rstd);
        }
        __syncthreads();
        #pragma unroll
        for (int m = 0; m < 4; ++m)
            #pragma unroll
            for (int i = 0; i < 4; ++i) {
                int r = 16 * m + 4 * lg + i;
                float2 mr = redp[r * 4];
                #pragma unroll
                for (int t = 0; t < 4; ++t) {
                    float y = (acc[m][t][i] - mr.x) * mr.y * sv[t] + bb[t];
                    sbuf[r * XSTR + w * 64 + t * 16 + l15] = f2bf(fmaxf(y, 0.f));
                }
            }
    }
    __syncthreads();

    // ---- GEMM2 (256x256) reading h0 from sbuf ----
    #pragma unroll
    for (int m = 0; m < 4; ++m)
        #pragma unroll
        for (int t = 0; t < 4; ++t)
            acc[m][t] = (f32x4){0.f, 0.f, 0.f, 0.f};
    for (int s = 0; s < 8; ++s) {
        bf16x8 a[4];
        #pragma unroll
        for (int m = 0; m < 4; ++m)
            a[m] = *reinterpret_cast<const bf16x8*>(&sbuf[(16 * m + l15) * XSTR + 32 * s + 8 * lg]);
        #pragma unroll
        for (int t = 0; t < 4; ++t) {
            bf16x8 b = *reinterpret_cast<const bf16x8*>(W1p + (((s * 16 + w * 4 + t) * 64 + lane) << 3));
            #pragma unroll
            for (int m = 0; m < 4; ++m)
                acc[m][t] = __builtin_amdgcn_mfma_f32_16x16x32_bf16(a[m], b, acc[m][t], 0, 0, 0);
        }
    }

    // ---- LN1 + ReLU -> h1 (overwrites h0 in sbuf after barrier) ----
    {
        float bv[4], sv[4], bb[4];
        #pragma unroll
        for (int t = 0; t < 4; ++t) {
            int n = w * 64 + t * 16 + l15;
            bv[t] = b1[n]; sv[t] = mlp_ln1_s[n]; bb[t] = mlp_ln1_b[n];
        }
        #pragma unroll
        for (int m = 0; m < 4; ++m)
            #pragma unroll
            for (int t = 0; t < 4; ++t)
                #pragma unroll
                for (int i = 0; i < 4; ++i)
                    acc[m][t][i] += bv[t];
        #pragma unroll
        for (int m = 0; m < 4; ++m) {
            #pragma unroll
            for (int i = 0; i < 4; ++i) {
                float ps = acc[m][0][i] + acc[m][1][i] + acc[m][2][i] + acc[m][3][i];
                float pq = acc[m][0][i] * acc[m][0][i] + acc[m][1][i] * acc[m][1][i]
                         + acc[m][2][i] * acc[m][2][i] + acc[m][3][i] * acc[m][3][i];
                ps += __shfl_xor(ps, 1); ps += __shfl_xor(ps, 2); ps += __shfl_xor(ps, 4); ps += __shfl_xor(ps, 8);
                pq += __shfl_xor(pq, 1); pq += __shfl_xor(pq, 2); pq += __shfl_xor(pq, 4); pq += __shfl_xor(pq, 8);
                if (l15 == 0) redp[(16 * m + 4 * lg + i) * 4 + w] = make_float2(ps, pq);
            }
        }
        __syncthreads();   // also guarantees all GEMM2 LDS reads are done
        if (tid < BM) {
            float2 a0 = redp[tid * 4 + 0], a1 = redp[tid * 4 + 1], a2 = redp[tid * 4 + 2], a3 = redp[tid * 4 + 3];
            float s  = a0.x + a1.x + a2.x + a3.x;
            float q  = a0.y + a1.y + a2.y + a3.y;
            float mu = s * (1.f / 256.f);
            float rstd = rsqrtf(q * (1.f / 256.f) - mu * mu + EPSV);
            redp[tid * 4 + 0] = make_float2(mu, rstd);
        }
        __syncthreads();
        #pragma unroll
        for (int m = 0; m < 4; ++m)
            #pragma unroll
            for (int i = 0; i < 4; ++i) {
                int r = 16 * m + 4 * lg + i;
                float2 mr = redp[r * 4];
                #pragma unroll
                for (int t = 0; t < 4; ++t) {
                    float y = (acc[m][t][i] - mr.x) * mr.y * sv[t] + bb[t];
                    sbuf[r * XSTR + w * 64 + t * 16 + l15] = f2bf(fmaxf(y, 0.f));
                }
            }
    }
    __syncthreads();

    // ---- GEMM3 (256x144): wave w owns rows 16w..16w+15, full N=144 ----
    f32x4 acc3[9];
    #pragma unroll
    for (int t = 0; t < 9; ++t) acc3[t] = (f32x4){0.f, 0.f, 0.f, 0.f};
    {
        const unsigned short* arow = sbuf + (16 * w + l15) * XSTR;
        for (int s = 0; s < 8; ++s) {
            bf16x8 a = *reinterpret_cast<const bf16x8*>(arow + 32 * s + 8 * lg);
            #pragma unroll
            for (int t = 0; t < 9; ++t) {
                bf16x8 b = *reinterpret_cast<const bf16x8*>(W2p + (((s * 9 + t) * 64 + lane) << 3));
                acc3[t] = __builtin_amdgcn_mfma_f32_16x16x32_bf16(a, b, acc3[t], 0, 0, 0);
            }
        }
    }
    // delta (f32) into sbuf alias — same 592B row pitch, wave-private rows
    float* delta = reinterpret_cast<float*>(sbuf);
    #pragma unroll
    for (int t = 0; t < 9; ++t)
        #pragma unroll
        for (int i = 0; i < 4; ++i)
            delta[(16 * w + 4 * lg + i) * DSTR + 16 * t + l15] = acc3[t][i];
    __syncthreads();

    // ---- epilogue: out = mask ? base + delta + b2 : base ----
    #pragma unroll
    for (int j = 0; j < 9; ++j) {
        int idx = tid + j * 256;          // 0..2303 ; 36 float4 per row
        int r = idx / 36, c4 = idx % 36;
        int grow = row0 + r;
        float4 d  = *reinterpret_cast<const float4*>(delta + r * DSTR + 4 * c4);
        float4 bb = *reinterpret_cast<const float4*>(b2 + 4 * c4);
        float4 base;
        if (c4 < 4) base = *reinterpret_cast<const float4*>(logits + (size_t)grow * 16 + 4 * c4);
        else        base = *reinterpret_cast<const float4*>(hidden + (size_t)grow * 128 + 4 * c4 - 16);
        const bool mk = lyr[r] > 0;
        float4 o;
        o.x = mk ? base.x + d.x + bb.x : base.x;
        o.y = mk ? base.y + d.y + bb.y : base.y;
        o.z = mk ? base.z + d.z + bb.z : base.z;
        o.w = mk ? base.w + d.w + bb.w : base.w;
        *reinterpret_cast<float4*>(out + (size_t)grow * 144 + 4 * c4) = o;
    }
}

extern "C" void kernel_launch(void* const* d_in, const int* in_sizes, int n_in,
                              void* d_out, int out_size, void* d_ws, size_t ws_size,
                              hipStream_t stream)
{
    const float* logits        = (const float*)d_in[0];
    const float* hidden        = (const float*)d_in[1];
    const float* layer_pe      = (const float*)d_in[2];
    const float* intra         = (const float*)d_in[3];
    // d_in[4] = loss: unused (LN of a scalar == its bias)
    const int*   layer         = (const int*)  d_in[5];
    const float* msg           = (const float*)d_in[6];
    const float* ln_logits_s   = (const float*)d_in[7];
    const float* ln_logits_b   = (const float*)d_in[8];
    const float* ln_hidden_s   = (const float*)d_in[9];
    const float* ln_hidden_b   = (const float*)d_in[10];
    const float* ln_layer_pe_s = (const float*)d_in[11];
    const float* ln_layer_pe_b = (const float*)d_in[12];
    const float* ln_intra_pe_s = (const float*)d_in[13];
    const float* ln_intra_pe_b = (const float*)d_in[14];
    // d_in[15] = ln_loss_s: unused
    const float* ln_loss_b     = (const float*)d_in[16];
    const float* ln_msg_s      = (const float*)d_in[17];
    const float* ln_msg_b      = (const float*)d_in[18];
    const float* W0            = (const float*)d_in[19];
    const float* b0            = (const float*)d_in[20];
    const float* mlp_ln0_s     = (const float*)d_in[21];
    const float* mlp_ln0_b     = (const float*)d_in[22];
    const float* W1            = (const float*)d_in[23];
    const float* b1            = (const float*)d_in[24];
    const float* mlp_ln1_s     = (const float*)d_in[25];
    const float* mlp_ln1_b     = (const float*)d_in[26];
    const float* W2            = (const float*)d_in[27];
    const float* b2            = (const float*)d_in[28];
    float* out = (float*)d_out;

    // workspace layout (485 KB): W0p | W1p | W2p | b0_eff
    unsigned short* W0p = (unsigned short*)d_ws;                     // 278528 B
    unsigned short* W1p = (unsigned short*)((char*)d_ws + 278528);   // 131072 B
    unsigned short* W2p = (unsigned short*)((char*)d_ws + 409600);   //  73728 B
    float*          b0e = (float*)((char*)d_ws + 483328);            //   1024 B

    prep_kernel<<<119, 256, 0, stream>>>(W0, b0, ln_loss_b, W1, W2, W0p, W1p, W2p, b0e);

    const int N = in_sizes[5];               // 200000, divisible by BM=64
    node_update_kernel<<<N / BM, 256, 0, stream>>>(
        logits, hidden, layer_pe, intra, layer, msg,
        ln_logits_s, ln_logits_b, ln_hidden_s, ln_hidden_b,
        ln_layer_pe_s, ln_layer_pe_b, ln_intra_pe_s, ln_intra_pe_b,
        ln_msg_s, ln_msg_b,
        W0p, b0e, mlp_ln0_s, mlp_ln0_b,
        W1p, b1, mlp_ln1_s, mlp_ln1_b,
        W2p, b2, out);
}

// Round 4
// 433.124 us; speedup vs baseline: 1.2404x; 1.2404x over previous
//
#include <hip/hip_runtime.h>
#include <hip/hip_bf16.h>

#define EPSV 1e-5f
#define BM   64
#define XSTR 296   // unified row stride (bf16): 592 B = 16B-aligned; also f32 delta stride 148
#define DSTR 148   // delta row stride (f32) == XSTR*2 bytes

using bf16x8 = __attribute__((ext_vector_type(8))) short;
using f32x4  = __attribute__((ext_vector_type(4))) float;
using us4    = __attribute__((ext_vector_type(4))) unsigned short;
using us8    = __attribute__((ext_vector_type(8))) unsigned short;

__device__ __forceinline__ unsigned short f2bf(float f) {
    unsigned int u = __float_as_uint(f);
    u += 0x7fffu + ((u >> 16) & 1u);   // RNE
    return (unsigned short)(u >> 16);
}

// ---------------- weight prep ----------------
// Fragment storage: ((s*NT + t)*64 + lane)*8 + i  holds  W[k = 32*s + 8*(lane>>4) + i][n = 16*t + (lane&15)]
// Packed-K order for W0: [logits 0..15 | hidden 16..143 | msg 144..287 | layer_pe 288..415 | intra 416..543]
//   orig row = k<144 ? k : (k<288 ? k+257 : k-144);  row 400 (loss) folded into b0_eff.
__global__ void prep_kernel(const float* __restrict__ W0, const float* __restrict__ b0,
                            const float* __restrict__ ln_loss_b,
                            const float* __restrict__ W1, const float* __restrict__ W2,
                            unsigned short* __restrict__ W0p, unsigned short* __restrict__ W1p,
                            unsigned short* __restrict__ W2p, float* __restrict__ b0e)
{
    int gtid = blockIdx.x * blockDim.x + threadIdx.x;
    if (gtid < 17408) {                       // W0p: 17 ksteps x 16 ntiles
        int lane = gtid & 63, fid = gtid >> 6;
        int s = fid >> 4, t = fid & 15;
        int n  = (t << 4) + (lane & 15);
        int kb = (s << 5) + ((lane >> 4) << 3);
        us8 v;
        #pragma unroll
        for (int i = 0; i < 8; ++i) {
            int k = kb + i;
            int orig = (k < 144) ? k : ((k < 288) ? (k + 257) : (k - 144));
            v[i] = f2bf(W0[orig * 256 + n]);
        }
        *reinterpret_cast<us8*>(W0p + gtid * 8) = v;
    } else if (gtid < 17408 + 8192) {         // W1p: 8 x 16
        int g = gtid - 17408;
        int lane = g & 63, fid = g >> 6;
        int s = fid >> 4, t = fid & 15;
        int n  = (t << 4) + (lane & 15);
        int kb = (s << 5) + ((lane >> 4) << 3);
        us8 v;
        #pragma unroll
        for (int i = 0; i < 8; ++i) v[i] = f2bf(W1[(kb + i) * 256 + n]);
        *reinterpret_cast<us8*>(W1p + g * 8) = v;
    } else if (gtid < 17408 + 8192 + 4608) {  // W2p: 8 x 9
        int g = gtid - 17408 - 8192;
        int lane = g & 63, fid = g >> 6;
        int s = fid / 9, t = fid % 9;
        int n  = (t << 4) + (lane & 15);
        int kb = (s << 5) + ((lane >> 4) << 3);
        us8 v;
        #pragma unroll
        for (int i = 0; i < 8; ++i) v[i] = f2bf(W2[(kb + i) * 144 + n]);
        *reinterpret_cast<us8*>(W2p + g * 8) = v;
    } else if (gtid < 17408 + 8192 + 4608 + 256) {
        int n = gtid - (17408 + 8192 + 4608);
        b0e[n] = b0[n] + ln_loss_b[0] * W0[400 * 256 + n];
    }
}

// ---------------- input LN staging: 4 threads per row ----------------
template<int L>
__device__ __forceinline__ void stage_seg(
    const float* __restrict__ src, int stride,
    const float* __restrict__ sc, const float* __restrict__ bi,
    unsigned short* xb, int dstcol, int tid, int row0)
{
    const int r = tid >> 2, sub = tid & 3;
    constexpr int PT = L / 4;
    constexpr int NV = PT / 4;
    const float* p = src + (size_t)(row0 + r) * stride + sub * PT;
    float4 v[NV];
    float ps = 0.f, pq = 0.f;
    #pragma unroll
    for (int j = 0; j < NV; ++j) {
        v[j] = *reinterpret_cast<const float4*>(p + 4 * j);
        ps += v[j].x + v[j].y + v[j].z + v[j].w;
        pq += v[j].x * v[j].x + v[j].y * v[j].y + v[j].z * v[j].z + v[j].w * v[j].w;
    }
    ps += __shfl_xor(ps, 1); ps += __shfl_xor(ps, 2);
    pq += __shfl_xor(pq, 1); pq += __shfl_xor(pq, 2);
    const float mu   = ps * (1.f / L);
    const float rstd = rsqrtf(pq * (1.f / L) - mu * mu + EPSV);
    unsigned short* dst = xb + r * XSTR + dstcol + sub * PT;
    const float* scp = sc + sub * PT;
    const float* bip = bi + sub * PT;
    #pragma unroll
    for (int j = 0; j < NV; ++j) {
        float4 sv = *reinterpret_cast<const float4*>(scp + 4 * j);
        float4 bv = *reinterpret_cast<const float4*>(bip + 4 * j);
        us4 o;
        o[0] = f2bf((v[j].x - mu) * rstd * sv.x + bv.x);
        o[1] = f2bf((v[j].y - mu) * rstd * sv.y + bv.y);
        o[2] = f2bf((v[j].z - mu) * rstd * sv.z + bv.z);
        o[3] = f2bf((v[j].w - mu) * rstd * sv.w + bv.w);
        *reinterpret_cast<us4*>(dst + 4 * j) = o;
    }
}

// ---------------- fused main kernel ----------------
// Single LDS buffer lifecycle (all transitions barrier-separated):
//   x chunk1 (288 cols) -> x chunk2 (256 cols) -> h0 (256) -> h1 (256) -> delta f32 (144)
// __launch_bounds__(256,3): cap = 170 unified regs >= natural ~160 alloc -> NO spill,
// LDS 3*40448 = 121 KB <= 160 KB -> 3 blocks/CU, 12 waves/CU.
__global__ __launch_bounds__(256, 3) void node_update_kernel(
    const float* __restrict__ logits, const float* __restrict__ hidden,
    const float* __restrict__ layer_pe, const float* __restrict__ intra,
    const int* __restrict__ layer, const float* __restrict__ msg,
    const float* __restrict__ ln_logits_s, const float* __restrict__ ln_logits_b,
    const float* __restrict__ ln_hidden_s, const float* __restrict__ ln_hidden_b,
    const float* __restrict__ ln_layer_pe_s, const float* __restrict__ ln_layer_pe_b,
    const float* __restrict__ ln_intra_pe_s, const float* __restrict__ ln_intra_pe_b,
    const float* __restrict__ ln_msg_s, const float* __restrict__ ln_msg_b,
    const unsigned short* __restrict__ W0p, const float* __restrict__ b0e,
    const float* __restrict__ mlp_ln0_s, const float* __restrict__ mlp_ln0_b,
    const unsigned short* __restrict__ W1p, const float* __restrict__ b1,
    const float* __restrict__ mlp_ln1_s, const float* __restrict__ mlp_ln1_b,
    const unsigned short* __restrict__ W2p, const float* __restrict__ b2,
    float* __restrict__ out)
{
    __shared__ __align__(16) unsigned short sbuf[BM * XSTR];  // 37888 B, multi-purpose
    __shared__ __align__(16) float redf[BM * 4 * 2];          // 2048 B
    __shared__ int lyr[BM];

    float2* redp = reinterpret_cast<float2*>(redf);
    const int tid  = threadIdx.x;
    const int lane = tid & 63;
    const int w    = tid >> 6;
    const int l15  = lane & 15;
    const int lg   = lane >> 4;
    const int row0 = blockIdx.x * BM;

    // ---- phase A: stage chunk1 (logits|hidden|msg = 288 cols) ----
    stage_seg<16 >(logits,   16, ln_logits_s,   ln_logits_b,   sbuf,   0, tid, row0);
    stage_seg<128>(hidden,  128, ln_hidden_s,   ln_hidden_b,   sbuf,  16, tid, row0);
    stage_seg<144>(msg,     144, ln_msg_s,      ln_msg_b,      sbuf, 144, tid, row0);
    if (tid < BM) lyr[tid] = layer[row0 + tid];
    __syncthreads();

    // ---- GEMM1 (K=544), wave w owns output cols 64w..64w+63 ----
    f32x4 acc[4][4];
    #pragma unroll
    for (int m = 0; m < 4; ++m)
        #pragma unroll
        for (int t = 0; t < 4; ++t)
            acc[m][t] = (f32x4){0.f, 0.f, 0.f, 0.f};

    for (int s = 0; s < 9; ++s) {             // chunk1: k 0..287
        bf16x8 a[4];
        #pragma unroll
        for (int m = 0; m < 4; ++m)
            a[m] = *reinterpret_cast<const bf16x8*>(&sbuf[(16 * m + l15) * XSTR + 32 * s + 8 * lg]);
        #pragma unroll
        for (int t = 0; t < 4; ++t) {
            bf16x8 b = *reinterpret_cast<const bf16x8*>(W0p + (((s * 16 + w * 4 + t) * 64 + lane) << 3));
            #pragma unroll
            for (int m = 0; m < 4; ++m)
                acc[m][t] = __builtin_amdgcn_mfma_f32_16x16x32_bf16(a[m], b, acc[m][t], 0, 0, 0);
        }
    }
    __syncthreads();
    // ---- phase B: stage chunk2 (layer_pe|intra = 256 cols); acc is live ----
    stage_seg<128>(layer_pe, 128, ln_layer_pe_s, ln_layer_pe_b, sbuf,   0, tid, row0);
    stage_seg<128>(intra,    128, ln_intra_pe_s, ln_intra_pe_b, sbuf, 128, tid, row0);
    __syncthreads();
    for (int s = 0; s < 8; ++s) {             // chunk2: k 288..543 (global kstep s+9)
        bf16x8 a[4];
        #pragma unroll
        for (int m = 0; m < 4; ++m)
            a[m] = *reinterpret_cast<const bf16x8*>(&sbuf[(16 * m + l15) * XSTR + 32 * s + 8 * lg]);
        #pragma unroll
        for (int t = 0; t < 4; ++t) {
            bf16x8 b = *reinterpret_cast<const bf16x8*>(W0p + ((((s + 9) * 16 + w * 4 + t) * 64 + lane) << 3));
            #pragma unroll
            for (int m = 0; m < 4; ++m)
                acc[m][t] = __builtin_amdgcn_mfma_f32_16x16x32_bf16(a[m], b, acc[m][t], 0, 0, 0);
        }
    }

    // ---- LN0 + ReLU -> h0 (bf16, overwrites x in sbuf after barrier) ----
    {
        float bv[4], sv[4], bb[4];
        #pragma unroll
        for (int t = 0; t < 4; ++t) {
            int n = w * 64 + t * 16 + l15;
            bv[t] = b0e[n]; sv[t] = mlp_ln0_s[n]; bb[t] = mlp_ln0_b[n];
        }
        #pragma unroll
        for (int m = 0; m < 4; ++m)
            #pragma unroll
            for (int t = 0; t < 4; ++t)
                #pragma unroll
                for (int i = 0; i < 4; ++i)
                    acc[m][t][i] += bv[t];
        #pragma unroll
        for (int m = 0; m < 4; ++m) {
            #pragma unroll
            for (int i = 0; i < 4; ++i) {
                float ps = acc[m][0][i] + acc[m][1][i] + acc[m][2][i] + acc[m][3][i];
                float pq = acc[m][0][i] * acc[m][0][i] + acc[m][1][i] * acc[m][1][i]
                         + acc[m][2][i] * acc[m][2][i] + acc[m][3][i] * acc[m][3][i];
                ps += __shfl_xor(ps, 1); ps += __shfl_xor(ps, 2); ps += __shfl_xor(ps, 4); ps += __shfl_xor(ps, 8);
                pq += __shfl_xor(pq, 1); pq += __shfl_xor(pq, 2); pq += __shfl_xor(pq, 4); pq += __shfl_xor(pq, 8);
                if (l15 == 0) redp[(16 * m + 4 * lg + i) * 4 + w] = make_float2(ps, pq);
            }
        }
        __syncthreads();   // also guarantees all GEMM1-chunk2 LDS reads are done
        if (tid < BM) {
            float2 a0 = redp[tid * 4 + 0], a1 = redp[tid * 4 + 1], a2 = redp[tid * 4 + 2], a3 = redp[tid * 4 + 3];
            float s  = a0.x + a1.x + a2.x + a3.x;
            float q  = a0.y + a1.y + a2.y + a3.y;
            float mu = s * (1.f / 256.f);
            float rstd = rsqrtf(q * (1.f / 256.f) - mu * mu + EPSV);
            redp[tid * 4 + 0] = make_float2(mu, rstd);
        }
        __syncthreads();
        #pragma unroll
        for (int m = 0; m < 4; ++m)
            #pragma unroll
            for (int i = 0; i < 4; ++i) {
                int r = 16 * m + 4 * lg + i;
                float2 mr = redp[r * 4];
                #pragma unroll
                for (int t = 0; t < 4; ++t) {
                    float y = (acc[m][t][i] - mr.x) * mr.y * sv[t] + bb[t];
                    sbuf[r * XSTR + w * 64 + t * 16 + l15] = f2bf(fmaxf(y, 0.f));
                }
            }
    }
    __syncthreads();

    // ---- GEMM2 (256x256) reading h0 from sbuf ----
    #pragma unroll
    for (int m = 0; m < 4; ++m)
        #pragma unroll
        for (int t = 0; t < 4; ++t)
            acc[m][t] = (f32x4){0.f, 0.f, 0.f, 0.f};
    for (int s = 0; s < 8; ++s) {
        bf16x8 a[4];
        #pragma unroll
        for (int m = 0; m < 4; ++m)
            a[m] = *reinterpret_cast<const bf16x8*>(&sbuf[(16 * m + l15) * XSTR + 32 * s + 8 * lg]);
        #pragma unroll
        for (int t = 0; t < 4; ++t) {
            bf16x8 b = *reinterpret_cast<const bf16x8*>(W1p + (((s * 16 + w * 4 + t) * 64 + lane) << 3));
            #pragma unroll
            for (int m = 0; m < 4; ++m)
                acc[m][t] = __builtin_amdgcn_mfma_f32_16x16x32_bf16(a[m], b, acc[m][t], 0, 0, 0);
        }
    }

    // ---- LN1 + ReLU -> h1 (overwrites h0 in sbuf after barrier) ----
    {
        float bv[4], sv[4], bb[4];
        #pragma unroll
        for (int t = 0; t < 4; ++t) {
            int n = w * 64 + t * 16 + l15;
            bv[t] = b1[n]; sv[t] = mlp_ln1_s[n]; bb[t] = mlp_ln1_b[n];
        }
        #pragma unroll
        for (int m = 0; m < 4; ++m)
            #pragma unroll
            for (int t = 0; t < 4; ++t)
                #pragma unroll
                for (int i = 0; i < 4; ++i)
                    acc[m][t][i] += bv[t];
        #pragma unroll
        for (int m = 0; m < 4; ++m) {
            #pragma unroll
            for (int i = 0; i < 4; ++i) {
                float ps = acc[m][0][i] + acc[m][1][i] + acc[m][2][i] + acc[m][3][i];
                float pq = acc[m][0][i] * acc[m][0][i] + acc[m][1][i] * acc[m][1][i]
                         + acc[m][2][i] * acc[m][2][i] + acc[m][3][i] * acc[m][3][i];
                ps += __shfl_xor(ps, 1); ps += __shfl_xor(ps, 2); ps += __shfl_xor(ps, 4); ps += __shfl_xor(ps, 8);
                pq += __shfl_xor(pq, 1); pq += __shfl_xor(pq, 2); pq += __shfl_xor(pq, 4); pq += __shfl_xor(pq, 8);
                if (l15 == 0) redp[(16 * m + 4 * lg + i) * 4 + w] = make_float2(ps, pq);
            }
        }
        __syncthreads();   // also guarantees all GEMM2 LDS reads are done
        if (tid < BM) {
            float2 a0 = redp[tid * 4 + 0], a1 = redp[tid * 4 + 1], a2 = redp[tid * 4 + 2], a3 = redp[tid * 4 + 3];
            float s  = a0.x + a1.x + a2.x + a3.x;
            float q  = a0.y + a1.y + a2.y + a3.y;
            float mu = s * (1.f / 256.f);
            float rstd = rsqrtf(q * (1.f / 256.f) - mu * mu + EPSV);
            redp[tid * 4 + 0] = make_float2(mu, rstd);
        }
        __syncthreads();
        #pragma unroll
        for (int m = 0; m < 4; ++m)
            #pragma unroll
            for (int i = 0; i < 4; ++i) {
                int r = 16 * m + 4 * lg + i;
                float2 mr = redp[r * 4];
                #pragma unroll
                for (int t = 0; t < 4; ++t) {
                    float y = (acc[m][t][i] - mr.x) * mr.y * sv[t] + bb[t];
                    sbuf[r * XSTR + w * 64 + t * 16 + l15] = f2bf(fmaxf(y, 0.f));
                }
            }
    }
    __syncthreads();

    // ---- GEMM3 (256x144): wave w owns rows 16w..16w+15, full N=144 ----
    f32x4 acc3[9];
    #pragma unroll
    for (int t = 0; t < 9; ++t) acc3[t] = (f32x4){0.f, 0.f, 0.f, 0.f};
    {
        const unsigned short* arow = sbuf + (16 * w + l15) * XSTR;
        for (int s = 0; s < 8; ++s) {
            bf16x8 a = *reinterpret_cast<const bf16x8*>(arow + 32 * s + 8 * lg);
            #pragma unroll
            for (int t = 0; t < 9; ++t) {
                bf16x8 b = *reinterpret_cast<const bf16x8*>(W2p + (((s * 9 + t) * 64 + lane) << 3));
                acc3[t] = __builtin_amdgcn_mfma_f32_16x16x32_bf16(a, b, acc3[t], 0, 0, 0);
            }
        }
    }
    // delta (f32) into sbuf alias — same 592B row pitch, wave-private rows
    float* delta = reinterpret_cast<float*>(sbuf);
    #pragma unroll
    for (int t = 0; t < 9; ++t)
        #pragma unroll
        for (int i = 0; i < 4; ++i)
            delta[(16 * w + 4 * lg + i) * DSTR + 16 * t + l15] = acc3[t][i];
    __syncthreads();

    // ---- epilogue: out = mask ? base + delta + b2 : base ----
    #pragma unroll
    for (int j = 0; j < 9; ++j) {
        int idx = tid + j * 256;          // 0..2303 ; 36 float4 per row
        int r = idx / 36, c4 = idx % 36;
        int grow = row0 + r;
        float4 d  = *reinterpret_cast<const float4*>(delta + r * DSTR + 4 * c4);
        float4 bb = *reinterpret_cast<const float4*>(b2 + 4 * c4);
        float4 base;
        if (c4 < 4) base = *reinterpret_cast<const float4*>(logits + (size_t)grow * 16 + 4 * c4);
        else        base = *reinterpret_cast<const float4*>(hidden + (size_t)grow * 128 + 4 * c4 - 16);
        const bool mk = lyr[r] > 0;
        float4 o;
        o.x = mk ? base.x + d.x + bb.x : base.x;
        o.y = mk ? base.y + d.y + bb.y : base.y;
        o.z = mk ? base.z + d.z + bb.z : base.z;
        o.w = mk ? base.w + d.w + bb.w : base.w;
        *reinterpret_cast<float4*>(out + (size_t)grow * 144 + 4 * c4) = o;
    }
}

extern "C" void kernel_launch(void* const* d_in, const int* in_sizes, int n_in,
                              void* d_out, int out_size, void* d_ws, size_t ws_size,
                              hipStream_t stream)
{
    const float* logits        = (const float*)d_in[0];
    const float* hidden        = (const float*)d_in[1];
    const float* layer_pe      = (const float*)d_in[2];
    const float* intra         = (const float*)d_in[3];
    // d_in[4] = loss: unused (LN of a scalar == its bias)
    const int*   layer         = (const int*)  d_in[5];
    const float* msg           = (const float*)d_in[6];
    const float* ln_logits_s   = (const float*)d_in[7];
    const float* ln_logits_b   = (const float*)d_in[8];
    const float* ln_hidden_s   = (const float*)d_in[9];
    const float* ln_hidden_b   = (const float*)d_in[10];
    const float* ln_layer_pe_s = (const float*)d_in[11];
    const float* ln_layer_pe_b = (const float*)d_in[12];
    const float* ln_intra_pe_s = (const float*)d_in[13];
    const float* ln_intra_pe_b = (const float*)d_in[14];
    // d_in[15] = ln_loss_s: unused
    const float* ln_loss_b     = (const float*)d_in[16];
    const float* ln_msg_s      = (const float*)d_in[17];
    const float* ln_msg_b      = (const float*)d_in[18];
    const float* W0            = (const float*)d_in[19];
    const float* b0            = (const float*)d_in[20];
    const float* mlp_ln0_s     = (const float*)d_in[21];
    const float* mlp_ln0_b     = (const float*)d_in[22];
    const float* W1            = (const float*)d_in[23];
    const float* b1            = (const float*)d_in[24];
    const float* mlp_ln1_s     = (const float*)d_in[25];
    const float* mlp_ln1_b     = (const float*)d_in[26];
    const float* W2            = (const float*)d_in[27];
    const float* b2            = (const float*)d_in[28];
    float* out = (float*)d_out;

    // workspace layout (485 KB): W0p | W1p | W2p | b0_eff
    unsigned short* W0p = (unsigned short*)d_ws;                     // 278528 B
    unsigned short* W1p = (unsigned short*)((char*)d_ws + 278528);   // 131072 B
    unsigned short* W2p = (unsigned short*)((char*)d_ws + 409600);   //  73728 B
    float*          b0e = (float*)((char*)d_ws + 483328);            //   1024 B

    prep_kernel<<<119, 256, 0, stream>>>(W0, b0, ln_loss_b, W1, W2, W0p, W1p, W2p, b0e);

    const int N = in_sizes[5];               // 200000, divisible by BM=64
    node_update_kernel<<<N / BM, 256, 0, stream>>>(
        logits, hidden, layer_pe, intra, layer, msg,
        ln_logits_s, ln_logits_b, ln_hidden_s, ln_hidden_b,
        ln_layer_pe_s, ln_layer_pe_b, ln_intra_pe_s, ln_intra_pe_b,
        ln_msg_s, ln_msg_b,
        W0p, b0e, mlp_ln0_s, mlp_ln0_b,
        W1p, b1, mlp_ln1_s, mlp_ln1_b,
        W2p, b2, out);
}

// Round 5
// 414.182 us; speedup vs baseline: 1.2971x; 1.0457x over previous
//
#include <hip/hip_runtime.h>
#include <hip/hip_bf16.h>

#define EPSV 1e-5f
#define BM   32
#define XSTR 296   // unified row stride (bf16): 592 B = 16B-aligned; also f32 delta stride 148
#define DSTR 148   // delta row stride (f32) == XSTR*2 bytes

using bf16x8 = __attribute__((ext_vector_type(8))) short;
using f32x4  = __attribute__((ext_vector_type(4))) float;
using us4    = __attribute__((ext_vector_type(4))) unsigned short;
using us8    = __attribute__((ext_vector_type(8))) unsigned short;

__device__ __forceinline__ unsigned short f2bf(float f) {
    unsigned int u = __float_as_uint(f);
    u += 0x7fffu + ((u >> 16) & 1u);   // RNE
    return (unsigned short)(u >> 16);
}

// ---------------- weight prep ----------------
// Fragment storage: ((s*NT + t)*64 + lane)*8 + i  holds  W[k = 32*s + 8*(lane>>4) + i][n = 16*t + (lane&15)]
// Packed-K order for W0: [logits 0..15 | hidden 16..143 | msg 144..287 | layer_pe 288..415 | intra 416..543]
//   orig row = k<144 ? k : (k<288 ? k+257 : k-144);  row 400 (loss) folded into b0_eff.
__global__ void prep_kernel(const float* __restrict__ W0, const float* __restrict__ b0,
                            const float* __restrict__ ln_loss_b,
                            const float* __restrict__ W1, const float* __restrict__ W2,
                            unsigned short* __restrict__ W0p, unsigned short* __restrict__ W1p,
                            unsigned short* __restrict__ W2p, float* __restrict__ b0e)
{
    int gtid = blockIdx.x * blockDim.x + threadIdx.x;
    if (gtid < 17408) {                       // W0p: 17 ksteps x 16 ntiles
        int lane = gtid & 63, fid = gtid >> 6;
        int s = fid >> 4, t = fid & 15;
        int n  = (t << 4) + (lane & 15);
        int kb = (s << 5) + ((lane >> 4) << 3);
        us8 v;
        #pragma unroll
        for (int i = 0; i < 8; ++i) {
            int k = kb + i;
            int orig = (k < 144) ? k : ((k < 288) ? (k + 257) : (k - 144));
            v[i] = f2bf(W0[orig * 256 + n]);
        }
        *reinterpret_cast<us8*>(W0p + gtid * 8) = v;
    } else if (gtid < 17408 + 8192) {         // W1p: 8 x 16
        int g = gtid - 17408;
        int lane = g & 63, fid = g >> 6;
        int s = fid >> 4, t = fid & 15;
        int n  = (t << 4) + (lane & 15);
        int kb = (s << 5) + ((lane >> 4) << 3);
        us8 v;
        #pragma unroll
        for (int i = 0; i < 8; ++i) v[i] = f2bf(W1[(kb + i) * 256 + n]);
        *reinterpret_cast<us8*>(W1p + g * 8) = v;
    } else if (gtid < 17408 + 8192 + 4608) {  // W2p: 8 x 9
        int g = gtid - 17408 - 8192;
        int lane = g & 63, fid = g >> 6;
        int s = fid / 9, t = fid % 9;
        int n  = (t << 4) + (lane & 15);
        int kb = (s << 5) + ((lane >> 4) << 3);
        us8 v;
        #pragma unroll
        for (int i = 0; i < 8; ++i) v[i] = f2bf(W2[(kb + i) * 144 + n]);
        *reinterpret_cast<us8*>(W2p + g * 8) = v;
    } else if (gtid < 17408 + 8192 + 4608 + 256) {
        int n = gtid - (17408 + 8192 + 4608);
        b0e[n] = b0[n] + ln_loss_b[0] * W0[400 * 256 + n];
    }
}

// ---------------- input LN staging: 8 threads per row, 32 rows ----------------
// Thread covers contiguous span = L/8 elements at offset sub*span.
// float4 loads when span%4==0 (16B-aligned), else float2.
template<int L>
__device__ __forceinline__ void stage8(
    const float* __restrict__ src,
    const float* __restrict__ sc, const float* __restrict__ bi,
    unsigned short* xb, int dstcol, int tid, int row0)
{
    constexpr int SPAN = L / 8;
    const int sub = tid & 7;
    const int r   = tid >> 3;                  // 0..31
    const float* p = src + (size_t)(row0 + r) * L + sub * SPAN;
    float ps = 0.f, pq = 0.f;
    if constexpr (SPAN % 4 == 0) {
        constexpr int NV = SPAN / 4;
        float4 v[NV];
        #pragma unroll
        for (int j = 0; j < NV; ++j) {
            v[j] = *reinterpret_cast<const float4*>(p + 4 * j);
            ps += v[j].x + v[j].y + v[j].z + v[j].w;
            pq += v[j].x * v[j].x + v[j].y * v[j].y + v[j].z * v[j].z + v[j].w * v[j].w;
        }
        ps += __shfl_xor(ps, 1); ps += __shfl_xor(ps, 2); ps += __shfl_xor(ps, 4);
        pq += __shfl_xor(pq, 1); pq += __shfl_xor(pq, 2); pq += __shfl_xor(pq, 4);
        const float mu   = ps * (1.f / L);
        const float rstd = rsqrtf(pq * (1.f / L) - mu * mu + EPSV);
        unsigned short* dst = xb + r * XSTR + dstcol + sub * SPAN;
        const float* scp = sc + sub * SPAN;
        const float* bip = bi + sub * SPAN;
        #pragma unroll
        for (int j = 0; j < NV; ++j) {
            float4 sv = *reinterpret_cast<const float4*>(scp + 4 * j);
            float4 bv = *reinterpret_cast<const float4*>(bip + 4 * j);
            us4 o;
            o[0] = f2bf((v[j].x - mu) * rstd * sv.x + bv.x);
            o[1] = f2bf((v[j].y - mu) * rstd * sv.y + bv.y);
            o[2] = f2bf((v[j].z - mu) * rstd * sv.z + bv.z);
            o[3] = f2bf((v[j].w - mu) * rstd * sv.w + bv.w);
            *reinterpret_cast<us4*>(dst + 4 * j) = o;
        }
    } else {
        constexpr int NV = SPAN / 2;
        float2 v[NV];
        #pragma unroll
        for (int j = 0; j < NV; ++j) {
            v[j] = *reinterpret_cast<const float2*>(p + 2 * j);
            ps += v[j].x + v[j].y;
            pq += v[j].x * v[j].x + v[j].y * v[j].y;
        }
        ps += __shfl_xor(ps, 1); ps += __shfl_xor(ps, 2); ps += __shfl_xor(ps, 4);
        pq += __shfl_xor(pq, 1); pq += __shfl_xor(pq, 2); pq += __shfl_xor(pq, 4);
        const float mu   = ps * (1.f / L);
        const float rstd = rsqrtf(pq * (1.f / L) - mu * mu + EPSV);
        unsigned short* dst = xb + r * XSTR + dstcol + sub * SPAN;
        const float* scp = sc + sub * SPAN;
        const float* bip = bi + sub * SPAN;
        #pragma unroll
        for (int j = 0; j < NV; ++j) {
            float2 sv = *reinterpret_cast<const float2*>(scp + 2 * j);
            float2 bv = *reinterpret_cast<const float2*>(bip + 2 * j);
            unsigned int pk = (unsigned int)f2bf((v[j].x - mu) * rstd * sv.x + bv.x)
                            | ((unsigned int)f2bf((v[j].y - mu) * rstd * sv.y + bv.y) << 16);
            *reinterpret_cast<unsigned int*>(dst + 2 * j) = pk;
        }
    }
}

// ---------------- fused main kernel ----------------
// BM=32 rows/block, 4 waves. Wave w: GEMM1/2 tile = rows 0..31 (m=0,1) x cols 64w..64w+63.
// acc[2][4] = 32 AGPR -> natural unified demand ~112 <= 128 cap -> no spill at 4 waves/SIMD.
// LDS lifecycle: x chunk1 (288) -> x chunk2 (256) -> h0 -> h1 -> delta f32 (144)
__global__ __launch_bounds__(256, 4) void node_update_kernel(
    const float* __restrict__ logits, const float* __restrict__ hidden,
    const float* __restrict__ layer_pe, const float* __restrict__ intra,
    const int* __restrict__ layer, const float* __restrict__ msg,
    const float* __restrict__ ln_logits_s, const float* __restrict__ ln_logits_b,
    const float* __restrict__ ln_hidden_s, const float* __restrict__ ln_hidden_b,
    const float* __restrict__ ln_layer_pe_s, const float* __restrict__ ln_layer_pe_b,
    const float* __restrict__ ln_intra_pe_s, const float* __restrict__ ln_intra_pe_b,
    const float* __restrict__ ln_msg_s, const float* __restrict__ ln_msg_b,
    const unsigned short* __restrict__ W0p, const float* __restrict__ b0e,
    const float* __restrict__ mlp_ln0_s, const float* __restrict__ mlp_ln0_b,
    const unsigned short* __restrict__ W1p, const float* __restrict__ b1,
    const float* __restrict__ mlp_ln1_s, const float* __restrict__ mlp_ln1_b,
    const unsigned short* __restrict__ W2p, const float* __restrict__ b2,
    float* __restrict__ out)
{
    __shared__ __align__(16) unsigned short sbuf[BM * XSTR];  // 18944 B, multi-purpose
    __shared__ __align__(16) float redf[BM * 4 * 2];          // 1024 B
    __shared__ int lyr[BM];

    float2* redp = reinterpret_cast<float2*>(redf);
    const int tid  = threadIdx.x;
    const int lane = tid & 63;
    const int w    = tid >> 6;
    const int l15  = lane & 15;
    const int lg   = lane >> 4;
    const int row0 = blockIdx.x * BM;

    // ---- phase A: stage chunk1 (logits|hidden|msg = 288 cols) ----
    stage8<16 >(logits, ln_logits_s, ln_logits_b, sbuf,   0, tid, row0);
    stage8<128>(hidden, ln_hidden_s, ln_hidden_b, sbuf,  16, tid, row0);
    stage8<144>(msg,    ln_msg_s,    ln_msg_b,    sbuf, 144, tid, row0);
    if (tid < BM) lyr[tid] = layer[row0 + tid];
    __syncthreads();

    // ---- GEMM1 (K=544), wave w owns output cols 64w..64w+63, rows 0..31 ----
    f32x4 acc[2][4];
    #pragma unroll
    for (int m = 0; m < 2; ++m)
        #pragma unroll
        for (int t = 0; t < 4; ++t)
            acc[m][t] = (f32x4){0.f, 0.f, 0.f, 0.f};

    for (int s = 0; s < 9; ++s) {             // chunk1: k 0..287
        bf16x8 a[2];
        #pragma unroll
        for (int m = 0; m < 2; ++m)
            a[m] = *reinterpret_cast<const bf16x8*>(&sbuf[(16 * m + l15) * XSTR + 32 * s + 8 * lg]);
        #pragma unroll
        for (int t = 0; t < 4; ++t) {
            bf16x8 b = *reinterpret_cast<const bf16x8*>(W0p + (((s * 16 + w * 4 + t) * 64 + lane) << 3));
            #pragma unroll
            for (int m = 0; m < 2; ++m)
                acc[m][t] = __builtin_amdgcn_mfma_f32_16x16x32_bf16(a[m], b, acc[m][t], 0, 0, 0);
        }
    }
    __syncthreads();
    // ---- phase B: stage chunk2 (layer_pe|intra = 256 cols); acc is live ----
    stage8<128>(layer_pe, ln_layer_pe_s, ln_layer_pe_b, sbuf,   0, tid, row0);
    stage8<128>(intra,    ln_intra_pe_s, ln_intra_pe_b, sbuf, 128, tid, row0);
    __syncthreads();
    for (int s = 0; s < 8; ++s) {             // chunk2: k 288..543 (global kstep s+9)
        bf16x8 a[2];
        #pragma unroll
        for (int m = 0; m < 2; ++m)
            a[m] = *reinterpret_cast<const bf16x8*>(&sbuf[(16 * m + l15) * XSTR + 32 * s + 8 * lg]);
        #pragma unroll
        for (int t = 0; t < 4; ++t) {
            bf16x8 b = *reinterpret_cast<const bf16x8*>(W0p + ((((s + 9) * 16 + w * 4 + t) * 64 + lane) << 3));
            #pragma unroll
            for (int m = 0; m < 2; ++m)
                acc[m][t] = __builtin_amdgcn_mfma_f32_16x16x32_bf16(a[m], b, acc[m][t], 0, 0, 0);
        }
    }

    // ---- LN0 + ReLU -> h0 (bf16, overwrites x in sbuf after barrier) ----
    {
        float bv[4], sv[4], bb[4];
        #pragma unroll
        for (int t = 0; t < 4; ++t) {
            int n = w * 64 + t * 16 + l15;
            bv[t] = b0e[n]; sv[t] = mlp_ln0_s[n]; bb[t] = mlp_ln0_b[n];
        }
        #pragma unroll
        for (int m = 0; m < 2; ++m)
            #pragma unroll
            for (int t = 0; t < 4; ++t)
                #pragma unroll
                for (int i = 0; i < 4; ++i)
                    acc[m][t][i] += bv[t];
        #pragma unroll
        for (int m = 0; m < 2; ++m) {
            #pragma unroll
            for (int i = 0; i < 4; ++i) {
                float ps = acc[m][0][i] + acc[m][1][i] + acc[m][2][i] + acc[m][3][i];
                float pq = acc[m][0][i] * acc[m][0][i] + acc[m][1][i] * acc[m][1][i]
                         + acc[m][2][i] * acc[m][2][i] + acc[m][3][i] * acc[m][3][i];
                ps += __shfl_xor(ps, 1); ps += __shfl_xor(ps, 2); ps += __shfl_xor(ps, 4); ps += __shfl_xor(ps, 8);
                pq += __shfl_xor(pq, 1); pq += __shfl_xor(pq, 2); pq += __shfl_xor(pq, 4); pq += __shfl_xor(pq, 8);
                if (l15 == 0) redp[(16 * m + 4 * lg + i) * 4 + w] = make_float2(ps, pq);
            }
        }
        __syncthreads();   // also guarantees all GEMM1-chunk2 LDS reads are done
        if (tid < BM) {
            float2 a0 = redp[tid * 4 + 0], a1 = redp[tid * 4 + 1], a2 = redp[tid * 4 + 2], a3 = redp[tid * 4 + 3];
            float s  = a0.x + a1.x + a2.x + a3.x;
            float q  = a0.y + a1.y + a2.y + a3.y;
            float mu = s * (1.f / 256.f);
            float rstd = rsqrtf(q * (1.f / 256.f) - mu * mu + EPSV);
            redp[tid * 4 + 0] = make_float2(mu, rstd);
        }
        __syncthreads();
        #pragma unroll
        for (int m = 0; m < 2; ++m)
            #pragma unroll
            for (int i = 0; i < 4; ++i) {
                int r = 16 * m + 4 * lg + i;
                float2 mr = redp[r * 4];
                #pragma unroll
                for (int t = 0; t < 4; ++t) {
                    float y = (acc[m][t][i] - mr.x) * mr.y * sv[t] + bb[t];
                    sbuf[r * XSTR + w * 64 + t * 16 + l15] = f2bf(fmaxf(y, 0.f));
                }
            }
    }
    __syncthreads();

    // ---- GEMM2 (256x256) reading h0 from sbuf ----
    #pragma unroll
    for (int m = 0; m < 2; ++m)
        #pragma unroll
        for (int t = 0; t < 4; ++t)
            acc[m][t] = (f32x4){0.f, 0.f, 0.f, 0.f};
    for (int s = 0; s < 8; ++s) {
        bf16x8 a[2];
        #pragma unroll
        for (int m = 0; m < 2; ++m)
            a[m] = *reinterpret_cast<const bf16x8*>(&sbuf[(16 * m + l15) * XSTR + 32 * s + 8 * lg]);
        #pragma unroll
        for (int t = 0; t < 4; ++t) {
            bf16x8 b = *reinterpret_cast<const bf16x8*>(W1p + (((s * 16 + w * 4 + t) * 64 + lane) << 3));
            #pragma unroll
            for (int m = 0; m < 2; ++m)
                acc[m][t] = __builtin_amdgcn_mfma_f32_16x16x32_bf16(a[m], b, acc[m][t], 0, 0, 0);
        }
    }

    // ---- LN1 + ReLU -> h1 (overwrites h0 in sbuf after barrier) ----
    {
        float bv[4], sv[4], bb[4];
        #pragma unroll
        for (int t = 0; t < 4; ++t) {
            int n = w * 64 + t * 16 + l15;
            bv[t] = b1[n]; sv[t] = mlp_ln1_s[n]; bb[t] = mlp_ln1_b[n];
        }
        #pragma unroll
        for (int m = 0; m < 2; ++m)
            #pragma unroll
            for (int t = 0; t < 4; ++t)
                #pragma unroll
                for (int i = 0; i < 4; ++i)
                    acc[m][t][i] += bv[t];
        #pragma unroll
        for (int m = 0; m < 2; ++m) {
            #pragma unroll
            for (int i = 0; i < 4; ++i) {
                float ps = acc[m][0][i] + acc[m][1][i] + acc[m][2][i] + acc[m][3][i];
                float pq = acc[m][0][i] * acc[m][0][i] + acc[m][1][i] * acc[m][1][i]
                         + acc[m][2][i] * acc[m][2][i] + acc[m][3][i] * acc[m][3][i];
                ps += __shfl_xor(ps, 1); ps += __shfl_xor(ps, 2); ps += __shfl_xor(ps, 4); ps += __shfl_xor(ps, 8);
                pq += __shfl_xor(pq, 1); pq += __shfl_xor(pq, 2); pq += __shfl_xor(pq, 4); pq += __shfl_xor(pq, 8);
                if (l15 == 0) redp[(16 * m + 4 * lg + i) * 4 + w] = make_float2(ps, pq);
            }
        }
        __syncthreads();   // also guarantees all GEMM2 LDS reads are done
        if (tid < BM) {
            float2 a0 = redp[tid * 4 + 0], a1 = redp[tid * 4 + 1], a2 = redp[tid * 4 + 2], a3 = redp[tid * 4 + 3];
            float s  = a0.x + a1.x + a2.x + a3.x;
            float q  = a0.y + a1.y + a2.y + a3.y;
            float mu = s * (1.f / 256.f);
            float rstd = rsqrtf(q * (1.f / 256.f) - mu * mu + EPSV);
            redp[tid * 4 + 0] = make_float2(mu, rstd);
        }
        __syncthreads();
        #pragma unroll
        for (int m = 0; m < 2; ++m)
            #pragma unroll
            for (int i = 0; i < 4; ++i) {
                int r = 16 * m + 4 * lg + i;
                float2 mr = redp[r * 4];
                #pragma unroll
                for (int t = 0; t < 4; ++t) {
                    float y = (acc[m][t][i] - mr.x) * mr.y * sv[t] + bb[t];
                    sbuf[r * XSTR + w * 64 + t * 16 + l15] = f2bf(fmaxf(y, 0.f));
                }
            }
    }
    __syncthreads();

    // ---- GEMM3 (32x256 @ 256x144): wave w -> rows 16*(w&1).., col-half (w>>1) ----
    {
        const int rg = w & 1;            // row group: 0 -> rows 0..15, 1 -> rows 16..31
        const int ch = w >> 1;           // col half : 0 -> t 0..4,     1 -> t 5..8
        const unsigned short* arow = sbuf + (16 * rg + l15) * XSTR;
        float* delta = reinterpret_cast<float*>(sbuf);
        if (ch == 0) {
            f32x4 acc3[5];
            #pragma unroll
            for (int t = 0; t < 5; ++t) acc3[t] = (f32x4){0.f, 0.f, 0.f, 0.f};
            for (int s = 0; s < 8; ++s) {
                bf16x8 a = *reinterpret_cast<const bf16x8*>(arow + 32 * s + 8 * lg);
                #pragma unroll
                for (int t = 0; t < 5; ++t) {
                    bf16x8 b = *reinterpret_cast<const bf16x8*>(W2p + (((s * 9 + t) * 64 + lane) << 3));
                    acc3[t] = __builtin_amdgcn_mfma_f32_16x16x32_bf16(a, b, acc3[t], 0, 0, 0);
                }
            }
            __syncthreads();   // all LDS h1 reads done before overwriting with delta
            #pragma unroll
            for (int t = 0; t < 5; ++t)
                #pragma unroll
                for (int i = 0; i < 4; ++i)
                    delta[(16 * rg + 4 * lg + i) * DSTR + 16 * t + l15] = acc3[t][i];
        } else {
            f32x4 acc3[4];
            #pragma unroll
            for (int t = 0; t < 4; ++t) acc3[t] = (f32x4){0.f, 0.f, 0.f, 0.f};
            for (int s = 0; s < 8; ++s) {
                bf16x8 a = *reinterpret_cast<const bf16x8*>(arow + 32 * s + 8 * lg);
                #pragma unroll
                for (int t = 0; t < 4; ++t) {
                    bf16x8 b = *reinterpret_cast<const bf16x8*>(W2p + (((s * 9 + t + 5) * 64 + lane) << 3));
                    acc3[t] = __builtin_amdgcn_mfma_f32_16x16x32_bf16(a, b, acc3[t], 0, 0, 0);
                }
            }
            __syncthreads();   // matches the ch==0 barrier (uniform per block)
            #pragma unroll
            for (int t = 0; t < 4; ++t)
                #pragma unroll
                for (int i = 0; i < 4; ++i)
                    delta[(16 * rg + 4 * lg + i) * DSTR + 16 * (t + 5) + l15] = acc3[t][i];
        }
    }
    __syncthreads();

    // ---- epilogue: out = mask ? base + delta + b2 : base ----
    const float* delta = reinterpret_cast<const float*>(sbuf);
    #pragma unroll
    for (int j = 0; j < 5; ++j) {
        int idx = tid + j * 256;          // 0..1151 ; 36 float4 per row, 32 rows
        if (idx < BM * 36) {
            int r = idx / 36, c4 = idx % 36;
            int grow = row0 + r;
            float4 d  = *reinterpret_cast<const float4*>(delta + r * DSTR + 4 * c4);
            float4 bb = *reinterpret_cast<const float4*>(b2 + 4 * c4);
            float4 base;
            if (c4 < 4) base = *reinterpret_cast<const float4*>(logits + (size_t)grow * 16 + 4 * c4);
            else        base = *reinterpret_cast<const float4*>(hidden + (size_t)grow * 128 + 4 * c4 - 16);
            const bool mk = lyr[r] > 0;
            float4 o;
            o.x = mk ? base.x + d.x + bb.x : base.x;
            o.y = mk ? base.y + d.y + bb.y : base.y;
            o.z = mk ? base.z + d.z + bb.z : base.z;
            o.w = mk ? base.w + d.w + bb.w : base.w;
            *reinterpret_cast<float4*>(out + (size_t)grow * 144 + 4 * c4) = o;
        }
    }
}

extern "C" void kernel_launch(void* const* d_in, const int* in_sizes, int n_in,
                              void* d_out, int out_size, void* d_ws, size_t ws_size,
                              hipStream_t stream)
{
    const float* logits        = (const float*)d_in[0];
    const float* hidden        = (const float*)d_in[1];
    const float* layer_pe      = (const float*)d_in[2];
    const float* intra         = (const float*)d_in[3];
    // d_in[4] = loss: unused (LN of a scalar == its bias)
    const int*   layer         = (const int*)  d_in[5];
    const float* msg           = (const float*)d_in[6];
    const float* ln_logits_s   = (const float*)d_in[7];
    const float* ln_logits_b   = (const float*)d_in[8];
    const float* ln_hidden_s   = (const float*)d_in[9];
    const float* ln_hidden_b   = (const float*)d_in[10];
    const float* ln_layer_pe_s = (const float*)d_in[11];
    const float* ln_layer_pe_b = (const float*)d_in[12];
    const float* ln_intra_pe_s = (const float*)d_in[13];
    const float* ln_intra_pe_b = (const float*)d_in[14];
    // d_in[15] = ln_loss_s: unused
    const float* ln_loss_b     = (const float*)d_in[16];
    const float* ln_msg_s      = (const float*)d_in[17];
    const float* ln_msg_b      = (const float*)d_in[18];
    const float* W0            = (const float*)d_in[19];
    const float* b0            = (const float*)d_in[20];
    const float* mlp_ln0_s     = (const float*)d_in[21];
    const float* mlp_ln0_b     = (const float*)d_in[22];
    const float* W1            = (const float*)d_in[23];
    const float* b1            = (const float*)d_in[24];
    const float* mlp_ln1_s     = (const float*)d_in[25];
    const float* mlp_ln1_b     = (const float*)d_in[26];
    const float* W2            = (const float*)d_in[27];
    const float* b2            = (const float*)d_in[28];
    float* out = (float*)d_out;

    // workspace layout (485 KB): W0p | W1p | W2p | b0_eff
    unsigned short* W0p = (unsigned short*)d_ws;                     // 278528 B
    unsigned short* W1p = (unsigned short*)((char*)d_ws + 278528);   // 131072 B
    unsigned short* W2p = (unsigned short*)((char*)d_ws + 409600);   //  73728 B
    float*          b0e = (float*)((char*)d_ws + 483328);            //   1024 B

    prep_kernel<<<119, 256, 0, stream>>>(W0, b0, ln_loss_b, W1, W2, W0p, W1p, W2p, b0e);

    const int N = in_sizes[5];               // 200000, divisible by BM=32
    node_update_kernel<<<N / BM, 256, 0, stream>>>(
        logits, hidden, layer_pe, intra, layer, msg,
        ln_logits_s, ln_logits_b, ln_hidden_s, ln_hidden_b,
        ln_layer_pe_s, ln_layer_pe_b, ln_intra_pe_s, ln_intra_pe_b,
        ln_msg_s, ln_msg_b,
        W0p, b0e, mlp_ln0_s, mlp_ln0_b,
        W1p, b1, mlp_ln1_s, mlp_ln1_b,
        W2p, b2, out);
}

// Round 6
// 371.699 us; speedup vs baseline: 1.4454x; 1.1143x over previous
//
#include <hip/hip_runtime.h>
#include <hip/hip_bf16.h>

#define EPSV 1e-5f
#define BM   32
#define XSTR 552   // full-x row stride (bf16): 1104 B, 16B-aligned; holds 544 cols
#define DSTR 276   // delta row stride (f32) == XSTR/2

using bf16x8 = __attribute__((ext_vector_type(8))) short;
using f32x4  = __attribute__((ext_vector_type(4))) float;
using us4    = __attribute__((ext_vector_type(4))) unsigned short;
using us8    = __attribute__((ext_vector_type(8))) unsigned short;

__device__ __forceinline__ unsigned short f2bf(float f) {
    unsigned int u = __float_as_uint(f);
    u += 0x7fffu + ((u >> 16) & 1u);   // RNE
    return (unsigned short)(u >> 16);
}

// ---------------- weight prep ----------------
// Fragment storage: ((s*NT + t)*64 + lane)*8 + i  holds  W[k = 32*s + 8*(lane>>4) + i][n = 16*t + (lane&15)]
// Packed-K order for W0: [logits 0..15 | hidden 16..143 | msg 144..287 | layer_pe 288..415 | intra 416..543]
//   orig row = k<144 ? k : (k<288 ? k+257 : k-144);  row 400 (loss) folded into b0_eff.
__global__ void prep_kernel(const float* __restrict__ W0, const float* __restrict__ b0,
                            const float* __restrict__ ln_loss_b,
                            const float* __restrict__ W1, const float* __restrict__ W2,
                            unsigned short* __restrict__ W0p, unsigned short* __restrict__ W1p,
                            unsigned short* __restrict__ W2p, float* __restrict__ b0e)
{
    int gtid = blockIdx.x * blockDim.x + threadIdx.x;
    if (gtid < 17408) {                       // W0p: 17 ksteps x 16 ntiles
        int lane = gtid & 63, fid = gtid >> 6;
        int s = fid >> 4, t = fid & 15;
        int n  = (t << 4) + (lane & 15);
        int kb = (s << 5) + ((lane >> 4) << 3);
        us8 v;
        #pragma unroll
        for (int i = 0; i < 8; ++i) {
            int k = kb + i;
            int orig = (k < 144) ? k : ((k < 288) ? (k + 257) : (k - 144));
            v[i] = f2bf(W0[orig * 256 + n]);
        }
        *reinterpret_cast<us8*>(W0p + gtid * 8) = v;
    } else if (gtid < 17408 + 8192) {         // W1p: 8 x 16
        int g = gtid - 17408;
        int lane = g & 63, fid = g >> 6;
        int s = fid >> 4, t = fid & 15;
        int n  = (t << 4) + (lane & 15);
        int kb = (s << 5) + ((lane >> 4) << 3);
        us8 v;
        #pragma unroll
        for (int i = 0; i < 8; ++i) v[i] = f2bf(W1[(kb + i) * 256 + n]);
        *reinterpret_cast<us8*>(W1p + g * 8) = v;
    } else if (gtid < 17408 + 8192 + 4608) {  // W2p: 8 x 9
        int g = gtid - 17408 - 8192;
        int lane = g & 63, fid = g >> 6;
        int s = fid / 9, t = fid % 9;
        int n  = (t << 4) + (lane & 15);
        int kb = (s << 5) + ((lane >> 4) << 3);
        us8 v;
        #pragma unroll
        for (int i = 0; i < 8; ++i) v[i] = f2bf(W2[(kb + i) * 144 + n]);
        *reinterpret_cast<us8*>(W2p + g * 8) = v;
    } else if (gtid < 17408 + 8192 + 4608 + 256) {
        int n = gtid - (17408 + 8192 + 4608);
        b0e[n] = b0[n] + ln_loss_b[0] * W0[400 * 256 + n];
    }
}

// ---------------- input LN staging: 8 threads per row, 32 rows ----------------
template<int L>
__device__ __forceinline__ void stage8(
    const float* __restrict__ src,
    const float* __restrict__ sc, const float* __restrict__ bi,
    unsigned short* xb, int dstcol, int tid, int row0)
{
    constexpr int SPAN = L / 8;
    const int sub = tid & 7;
    const int r   = tid >> 3;                  // 0..31
    const float* p = src + (size_t)(row0 + r) * L + sub * SPAN;
    float ps = 0.f, pq = 0.f;
    if constexpr (SPAN % 4 == 0) {
        constexpr int NV = SPAN / 4;
        float4 v[NV];
        #pragma unroll
        for (int j = 0; j < NV; ++j) {
            v[j] = *reinterpret_cast<const float4*>(p + 4 * j);
            ps += v[j].x + v[j].y + v[j].z + v[j].w;
            pq += v[j].x * v[j].x + v[j].y * v[j].y + v[j].z * v[j].z + v[j].w * v[j].w;
        }
        ps += __shfl_xor(ps, 1); ps += __shfl_xor(ps, 2); ps += __shfl_xor(ps, 4);
        pq += __shfl_xor(pq, 1); pq += __shfl_xor(pq, 2); pq += __shfl_xor(pq, 4);
        const float mu   = ps * (1.f / L);
        const float rstd = rsqrtf(pq * (1.f / L) - mu * mu + EPSV);
        unsigned short* dst = xb + r * XSTR + dstcol + sub * SPAN;
        const float* scp = sc + sub * SPAN;
        const float* bip = bi + sub * SPAN;
        #pragma unroll
        for (int j = 0; j < NV; ++j) {
            float4 sv = *reinterpret_cast<const float4*>(scp + 4 * j);
            float4 bv = *reinterpret_cast<const float4*>(bip + 4 * j);
            us4 o;
            o[0] = f2bf((v[j].x - mu) * rstd * sv.x + bv.x);
            o[1] = f2bf((v[j].y - mu) * rstd * sv.y + bv.y);
            o[2] = f2bf((v[j].z - mu) * rstd * sv.z + bv.z);
            o[3] = f2bf((v[j].w - mu) * rstd * sv.w + bv.w);
            *reinterpret_cast<us4*>(dst + 4 * j) = o;
        }
    } else {
        constexpr int NV = SPAN / 2;
        float2 v[NV];
        #pragma unroll
        for (int j = 0; j < NV; ++j) {
            v[j] = *reinterpret_cast<const float2*>(p + 2 * j);
            ps += v[j].x + v[j].y;
            pq += v[j].x * v[j].x + v[j].y * v[j].y;
        }
        ps += __shfl_xor(ps, 1); ps += __shfl_xor(ps, 2); ps += __shfl_xor(ps, 4);
        pq += __shfl_xor(pq, 1); pq += __shfl_xor(pq, 2); pq += __shfl_xor(pq, 4);
        const float mu   = ps * (1.f / L);
        const float rstd = rsqrtf(pq * (1.f / L) - mu * mu + EPSV);
        unsigned short* dst = xb + r * XSTR + dstcol + sub * SPAN;
        const float* scp = sc + sub * SPAN;
        const float* bip = bi + sub * SPAN;
        #pragma unroll
        for (int j = 0; j < NV; ++j) {
            float2 sv = *reinterpret_cast<const float2*>(scp + 2 * j);
            float2 bv = *reinterpret_cast<const float2*>(bip + 2 * j);
            unsigned int pk = (unsigned int)f2bf((v[j].x - mu) * rstd * sv.x + bv.x)
                            | ((unsigned int)f2bf((v[j].y - mu) * rstd * sv.y + bv.y) << 16);
            *reinterpret_cast<unsigned int*>(dst + 2 * j) = pk;
        }
    }
}

// ---------------- fused main kernel ----------------
// BM=32, 4 waves. KEY CHANGE vs R5: ALL staging happens up front (full 544-col x
// buffer) -> no MFMA accumulator is live during any staging -> register peak
// stays < 128 -> no spill (WRITE_SIZE must return to 112500 KB).
// sched_barrier(0) between stage calls stops the compiler from merging the
// load batches of different segments (the liveness explosion seen in R2-R5).
// LDS lifecycle: x full (544) -> h0 (256, overwrites) -> h1 -> delta f32 (144)
__global__ __launch_bounds__(256, 4) void node_update_kernel(
    const float* __restrict__ logits, const float* __restrict__ hidden,
    const float* __restrict__ layer_pe, const float* __restrict__ intra,
    const int* __restrict__ layer, const float* __restrict__ msg,
    const float* __restrict__ ln_logits_s, const float* __restrict__ ln_logits_b,
    const float* __restrict__ ln_hidden_s, const float* __restrict__ ln_hidden_b,
    const float* __restrict__ ln_layer_pe_s, const float* __restrict__ ln_layer_pe_b,
    const float* __restrict__ ln_intra_pe_s, const float* __restrict__ ln_intra_pe_b,
    const float* __restrict__ ln_msg_s, const float* __restrict__ ln_msg_b,
    const unsigned short* __restrict__ W0p, const float* __restrict__ b0e,
    const float* __restrict__ mlp_ln0_s, const float* __restrict__ mlp_ln0_b,
    const unsigned short* __restrict__ W1p, const float* __restrict__ b1,
    const float* __restrict__ mlp_ln1_s, const float* __restrict__ mlp_ln1_b,
    const unsigned short* __restrict__ W2p, const float* __restrict__ b2,
    float* __restrict__ out)
{
    __shared__ __align__(16) unsigned short sbuf[BM * XSTR];  // 35328 B, multi-purpose
    __shared__ __align__(16) float redf[BM * 4 * 2];          // 1024 B
    __shared__ int lyr[BM];

    float2* redp = reinterpret_cast<float2*>(redf);
    const int tid  = threadIdx.x;
    const int lane = tid & 63;
    const int w    = tid >> 6;
    const int l15  = lane & 15;
    const int lg   = lane >> 4;
    const int row0 = blockIdx.x * BM;

    // ---- phase A: stage ALL 544 cols (no accumulator live) ----
    stage8<16 >(logits,   ln_logits_s,   ln_logits_b,   sbuf,   0, tid, row0);
    __builtin_amdgcn_sched_barrier(0);
    stage8<128>(hidden,   ln_hidden_s,   ln_hidden_b,   sbuf,  16, tid, row0);
    __builtin_amdgcn_sched_barrier(0);
    stage8<144>(msg,      ln_msg_s,      ln_msg_b,      sbuf, 144, tid, row0);
    __builtin_amdgcn_sched_barrier(0);
    stage8<128>(layer_pe, ln_layer_pe_s, ln_layer_pe_b, sbuf, 288, tid, row0);
    __builtin_amdgcn_sched_barrier(0);
    stage8<128>(intra,    ln_intra_pe_s, ln_intra_pe_b, sbuf, 416, tid, row0);
    __builtin_amdgcn_sched_barrier(0);
    if (tid < BM) lyr[tid] = layer[row0 + tid];
    __syncthreads();

    // ---- GEMM1 (K=544 in one loop), wave w owns cols 64w..64w+63, rows 0..31 ----
    f32x4 acc[2][4];
    #pragma unroll
    for (int m = 0; m < 2; ++m)
        #pragma unroll
        for (int t = 0; t < 4; ++t)
            acc[m][t] = (f32x4){0.f, 0.f, 0.f, 0.f};

    for (int s = 0; s < 17; ++s) {
        bf16x8 a[2];
        #pragma unroll
        for (int m = 0; m < 2; ++m)
            a[m] = *reinterpret_cast<const bf16x8*>(&sbuf[(16 * m + l15) * XSTR + 32 * s + 8 * lg]);
        #pragma unroll
        for (int t = 0; t < 4; ++t) {
            bf16x8 b = *reinterpret_cast<const bf16x8*>(W0p + (((s * 16 + w * 4 + t) * 64 + lane) << 3));
            #pragma unroll
            for (int m = 0; m < 2; ++m)
                acc[m][t] = __builtin_amdgcn_mfma_f32_16x16x32_bf16(a[m], b, acc[m][t], 0, 0, 0);
        }
    }

    // ---- LN0 + ReLU -> h0 (bf16, overwrites x in sbuf after barrier) ----
    {
        float bv[4], sv[4], bb[4];
        #pragma unroll
        for (int t = 0; t < 4; ++t) {
            int n = w * 64 + t * 16 + l15;
            bv[t] = b0e[n]; sv[t] = mlp_ln0_s[n]; bb[t] = mlp_ln0_b[n];
        }
        #pragma unroll
        for (int m = 0; m < 2; ++m)
            #pragma unroll
            for (int t = 0; t < 4; ++t)
                #pragma unroll
                for (int i = 0; i < 4; ++i)
                    acc[m][t][i] += bv[t];
        #pragma unroll
        for (int m = 0; m < 2; ++m) {
            #pragma unroll
            for (int i = 0; i < 4; ++i) {
                float ps = acc[m][0][i] + acc[m][1][i] + acc[m][2][i] + acc[m][3][i];
                float pq = acc[m][0][i] * acc[m][0][i] + acc[m][1][i] * acc[m][1][i]
                         + acc[m][2][i] * acc[m][2][i] + acc[m][3][i] * acc[m][3][i];
                ps += __shfl_xor(ps, 1); ps += __shfl_xor(ps, 2); ps += __shfl_xor(ps, 4); ps += __shfl_xor(ps, 8);
                pq += __shfl_xor(pq, 1); pq += __shfl_xor(pq, 2); pq += __shfl_xor(pq, 4); pq += __shfl_xor(pq, 8);
                if (l15 == 0) redp[(16 * m + 4 * lg + i) * 4 + w] = make_float2(ps, pq);
            }
        }
        __syncthreads();   // all GEMM1 LDS reads complete before h0 overwrite
        if (tid < BM) {
            float2 a0 = redp[tid * 4 + 0], a1 = redp[tid * 4 + 1], a2 = redp[tid * 4 + 2], a3 = redp[tid * 4 + 3];
            float s  = a0.x + a1.x + a2.x + a3.x;
            float q  = a0.y + a1.y + a2.y + a3.y;
            float mu = s * (1.f / 256.f);
            float rstd = rsqrtf(q * (1.f / 256.f) - mu * mu + EPSV);
            redp[tid * 4 + 0] = make_float2(mu, rstd);
        }
        __syncthreads();
        #pragma unroll
        for (int m = 0; m < 2; ++m)
            #pragma unroll
            for (int i = 0; i < 4; ++i) {
                int r = 16 * m + 4 * lg + i;
                float2 mr = redp[r * 4];
                #pragma unroll
                for (int t = 0; t < 4; ++t) {
                    float y = (acc[m][t][i] - mr.x) * mr.y * sv[t] + bb[t];
                    sbuf[r * XSTR + w * 64 + t * 16 + l15] = f2bf(fmaxf(y, 0.f));
                }
            }
    }
    __syncthreads();

    // ---- GEMM2 (256x256) reading h0 from sbuf ----
    #pragma unroll
    for (int m = 0; m < 2; ++m)
        #pragma unroll
        for (int t = 0; t < 4; ++t)
            acc[m][t] = (f32x4){0.f, 0.f, 0.f, 0.f};
    for (int s = 0; s < 8; ++s) {
        bf16x8 a[2];
        #pragma unroll
        for (int m = 0; m < 2; ++m)
            a[m] = *reinterpret_cast<const bf16x8*>(&sbuf[(16 * m + l15) * XSTR + 32 * s + 8 * lg]);
        #pragma unroll
        for (int t = 0; t < 4; ++t) {
            bf16x8 b = *reinterpret_cast<const bf16x8*>(W1p + (((s * 16 + w * 4 + t) * 64 + lane) << 3));
            #pragma unroll
            for (int m = 0; m < 2; ++m)
                acc[m][t] = __builtin_amdgcn_mfma_f32_16x16x32_bf16(a[m], b, acc[m][t], 0, 0, 0);
        }
    }

    // ---- LN1 + ReLU -> h1 (overwrites h0 in sbuf after barrier) ----
    {
        float bv[4], sv[4], bb[4];
        #pragma unroll
        for (int t = 0; t < 4; ++t) {
            int n = w * 64 + t * 16 + l15;
            bv[t] = b1[n]; sv[t] = mlp_ln1_s[n]; bb[t] = mlp_ln1_b[n];
        }
        #pragma unroll
        for (int m = 0; m < 2; ++m)
            #pragma unroll
            for (int t = 0; t < 4; ++t)
                #pragma unroll
                for (int i = 0; i < 4; ++i)
                    acc[m][t][i] += bv[t];
        #pragma unroll
        for (int m = 0; m < 2; ++m) {
            #pragma unroll
            for (int i = 0; i < 4; ++i) {
                float ps = acc[m][0][i] + acc[m][1][i] + acc[m][2][i] + acc[m][3][i];
                float pq = acc[m][0][i] * acc[m][0][i] + acc[m][1][i] * acc[m][1][i]
                         + acc[m][2][i] * acc[m][2][i] + acc[m][3][i] * acc[m][3][i];
                ps += __shfl_xor(ps, 1); ps += __shfl_xor(ps, 2); ps += __shfl_xor(ps, 4); ps += __shfl_xor(ps, 8);
                pq += __shfl_xor(pq, 1); pq += __shfl_xor(pq, 2); pq += __shfl_xor(pq, 4); pq += __shfl_xor(pq, 8);
                if (l15 == 0) redp[(16 * m + 4 * lg + i) * 4 + w] = make_float2(ps, pq);
            }
        }
        __syncthreads();   // all GEMM2 LDS reads complete
        if (tid < BM) {
            float2 a0 = redp[tid * 4 + 0], a1 = redp[tid * 4 + 1], a2 = redp[tid * 4 + 2], a3 = redp[tid * 4 + 3];
            float s  = a0.x + a1.x + a2.x + a3.x;
            float q  = a0.y + a1.y + a2.y + a3.y;
            float mu = s * (1.f / 256.f);
            float rstd = rsqrtf(q * (1.f / 256.f) - mu * mu + EPSV);
            redp[tid * 4 + 0] = make_float2(mu, rstd);
        }
        __syncthreads();
        #pragma unroll
        for (int m = 0; m < 2; ++m)
            #pragma unroll
            for (int i = 0; i < 4; ++i) {
                int r = 16 * m + 4 * lg + i;
                float2 mr = redp[r * 4];
                #pragma unroll
                for (int t = 0; t < 4; ++t) {
                    float y = (acc[m][t][i] - mr.x) * mr.y * sv[t] + bb[t];
                    sbuf[r * XSTR + w * 64 + t * 16 + l15] = f2bf(fmaxf(y, 0.f));
                }
            }
    }
    __syncthreads();

    // ---- GEMM3 (32x256 @ 256x144): wave w -> rows 16*(w&1).., col-half (w>>1) ----
    {
        const int rg = w & 1;            // row group: 0 -> rows 0..15, 1 -> rows 16..31
        const int ch = w >> 1;           // col half : 0 -> t 0..4,     1 -> t 5..8
        const unsigned short* arow = sbuf + (16 * rg + l15) * XSTR;
        float* delta = reinterpret_cast<float*>(sbuf);
        f32x4 acc3[5];
        const int NT = (ch == 0) ? 5 : 4;
        const int tofs = (ch == 0) ? 0 : 5;
        #pragma unroll
        for (int t = 0; t < 5; ++t) acc3[t] = (f32x4){0.f, 0.f, 0.f, 0.f};
        for (int s = 0; s < 8; ++s) {
            bf16x8 a = *reinterpret_cast<const bf16x8*>(arow + 32 * s + 8 * lg);
            for (int t = 0; t < NT; ++t) {
                bf16x8 b = *reinterpret_cast<const bf16x8*>(W2p + (((s * 9 + t + tofs) * 64 + lane) << 3));
                acc3[t] = __builtin_amdgcn_mfma_f32_16x16x32_bf16(a, b, acc3[t], 0, 0, 0);
            }
        }
        __syncthreads();   // all h1 LDS reads done before delta overwrite
        for (int t = 0; t < NT; ++t)
            #pragma unroll
            for (int i = 0; i < 4; ++i)
                delta[(16 * rg + 4 * lg + i) * DSTR + 16 * (t + tofs) + l15] = acc3[t][i];
    }
    __syncthreads();

    // ---- epilogue: out = mask ? base + delta + b2 : base ----
    const float* delta = reinterpret_cast<const float*>(sbuf);
    #pragma unroll
    for (int j = 0; j < 5; ++j) {
        int idx = tid + j * 256;          // 0..1151 ; 36 float4 per row, 32 rows
        if (idx < BM * 36) {
            int r = idx / 36, c4 = idx % 36;
            int grow = row0 + r;
            float4 d  = *reinterpret_cast<const float4*>(delta + r * DSTR + 4 * c4);
            float4 bb = *reinterpret_cast<const float4*>(b2 + 4 * c4);
            float4 base;
            if (c4 < 4) base = *reinterpret_cast<const float4*>(logits + (size_t)grow * 16 + 4 * c4);
            else        base = *reinterpret_cast<const float4*>(hidden + (size_t)grow * 128 + 4 * c4 - 16);
            const bool mk = lyr[r] > 0;
            float4 o;
            o.x = mk ? base.x + d.x + bb.x : base.x;
            o.y = mk ? base.y + d.y + bb.y : base.y;
            o.z = mk ? base.z + d.z + bb.z : base.z;
            o.w = mk ? base.w + d.w + bb.w : base.w;
            *reinterpret_cast<float4*>(out + (size_t)grow * 144 + 4 * c4) = o;
        }
    }
}

extern "C" void kernel_launch(void* const* d_in, const int* in_sizes, int n_in,
                              void* d_out, int out_size, void* d_ws, size_t ws_size,
                              hipStream_t stream)
{
    const float* logits        = (const float*)d_in[0];
    const float* hidden        = (const float*)d_in[1];
    const float* layer_pe      = (const float*)d_in[2];
    const float* intra         = (const float*)d_in[3];
    // d_in[4] = loss: unused (LN of a scalar == its bias)
    const int*   layer         = (const int*)  d_in[5];
    const float* msg           = (const float*)d_in[6];
    const float* ln_logits_s   = (const float*)d_in[7];
    const float* ln_logits_b   = (const float*)d_in[8];
    const float* ln_hidden_s   = (const float*)d_in[9];
    const float* ln_hidden_b   = (const float*)d_in[10];
    const float* ln_layer_pe_s = (const float*)d_in[11];
    const float* ln_layer_pe_b = (const float*)d_in[12];
    const float* ln_intra_pe_s = (const float*)d_in[13];
    const float* ln_intra_pe_b = (const float*)d_in[14];
    // d_in[15] = ln_loss_s: unused
    const float* ln_loss_b     = (const float*)d_in[16];
    const float* ln_msg_s      = (const float*)d_in[17];
    const float* ln_msg_b      = (const float*)d_in[18];
    const float* W0            = (const float*)d_in[19];
    const float* b0            = (const float*)d_in[20];
    const float* mlp_ln0_s     = (const float*)d_in[21];
    const float* mlp_ln0_b     = (const float*)d_in[22];
    const float* W1            = (const float*)d_in[23];
    const float* b1            = (const float*)d_in[24];
    const float* mlp_ln1_s     = (const float*)d_in[25];
    const float* mlp_ln1_b     = (const float*)d_in[26];
    const float* W2            = (const float*)d_in[27];
    const float* b2            = (const float*)d_in[28];
    float* out = (float*)d_out;

    // workspace layout (485 KB): W0p | W1p | W2p | b0_eff
    unsigned short* W0p = (unsigned short*)d_ws;                     // 278528 B
    unsigned short* W1p = (unsigned short*)((char*)d_ws + 278528);   // 131072 B
    unsigned short* W2p = (unsigned short*)((char*)d_ws + 409600);   //  73728 B
    float*          b0e = (float*)((char*)d_ws + 483328);            //   1024 B

    prep_kernel<<<119, 256, 0, stream>>>(W0, b0, ln_loss_b, W1, W2, W0p, W1p, W2p, b0e);

    const int N = in_sizes[5];               // 200000, divisible by BM=32
    node_update_kernel<<<N / BM, 256, 0, stream>>>(
        logits, hidden, layer_pe, intra, layer, msg,
        ln_logits_s, ln_logits_b, ln_hidden_s, ln_hidden_b,
        ln_layer_pe_s, ln_layer_pe_b, ln_intra_pe_s, ln_intra_pe_b,
        ln_msg_s, ln_msg_b,
        W0p, b0e, mlp_ln0_s, mlp_ln0_b,
        W1p, b1, mlp_ln1_s, mlp_ln1_b,
        W2p, b2, out);
}

// Round 7
// 308.669 us; speedup vs baseline: 1.7405x; 1.2042x over previous
//
#include <hip/hip_runtime.h>
#include <hip/hip_bf16.h>

#define EPSV 1e-5f
#define BM   32
#define XSTR 552   // full-x row stride (bf16): 1104 B, 16B-aligned; holds 544 cols
#define DSTR 276   // delta row stride (f32) == XSTR/2

using bf16x8 = __attribute__((ext_vector_type(8))) short;
using f32x4  = __attribute__((ext_vector_type(4))) float;
using us4    = __attribute__((ext_vector_type(4))) unsigned short;
using us8    = __attribute__((ext_vector_type(8))) unsigned short;

__device__ __forceinline__ unsigned short f2bf(float f) {
    unsigned int u = __float_as_uint(f);
    u += 0x7fffu + ((u >> 16) & 1u);   // RNE
    return (unsigned short)(u >> 16);
}

// ---------------- weight prep ----------------
// Fragment storage: ((s*NT + t)*64 + lane)*8 + i  holds  W[k = 32*s + 8*(lane>>4) + i][n = 16*t + (lane&15)]
// Packed-K order for W0: [logits 0..15 | hidden 16..143 | msg 144..287 | layer_pe 288..415 | intra 416..543]
//   orig row = k<144 ? k : (k<288 ? k+257 : k-144);  row 400 (loss) folded into b0_eff.
__global__ void prep_kernel(const float* __restrict__ W0, const float* __restrict__ b0,
                            const float* __restrict__ ln_loss_b,
                            const float* __restrict__ W1, const float* __restrict__ W2,
                            unsigned short* __restrict__ W0p, unsigned short* __restrict__ W1p,
                            unsigned short* __restrict__ W2p, float* __restrict__ b0e)
{
    int gtid = blockIdx.x * blockDim.x + threadIdx.x;
    if (gtid < 17408) {                       // W0p: 17 ksteps x 16 ntiles
        int lane = gtid & 63, fid = gtid >> 6;
        int s = fid >> 4, t = fid & 15;
        int n  = (t << 4) + (lane & 15);
        int kb = (s << 5) + ((lane >> 4) << 3);
        us8 v;
        #pragma unroll
        for (int i = 0; i < 8; ++i) {
            int k = kb + i;
            int orig = (k < 144) ? k : ((k < 288) ? (k + 257) : (k - 144));
            v[i] = f2bf(W0[orig * 256 + n]);
        }
        *reinterpret_cast<us8*>(W0p + gtid * 8) = v;
    } else if (gtid < 17408 + 8192) {         // W1p: 8 x 16
        int g = gtid - 17408;
        int lane = g & 63, fid = g >> 6;
        int s = fid >> 4, t = fid & 15;
        int n  = (t << 4) + (lane & 15);
        int kb = (s << 5) + ((lane >> 4) << 3);
        us8 v;
        #pragma unroll
        for (int i = 0; i < 8; ++i) v[i] = f2bf(W1[(kb + i) * 256 + n]);
        *reinterpret_cast<us8*>(W1p + g * 8) = v;
    } else if (gtid < 17408 + 8192 + 4608) {  // W2p: 8 x 9
        int g = gtid - 17408 - 8192;
        int lane = g & 63, fid = g >> 6;
        int s = fid / 9, t = fid % 9;
        int n  = (t << 4) + (lane & 15);
        int kb = (s << 5) + ((lane >> 4) << 3);
        us8 v;
        #pragma unroll
        for (int i = 0; i < 8; ++i) v[i] = f2bf(W2[(kb + i) * 144 + n]);
        *reinterpret_cast<us8*>(W2p + g * 8) = v;
    } else if (gtid < 17408 + 8192 + 4608 + 256) {
        int n = gtid - (17408 + 8192 + 4608);
        b0e[n] = b0[n] + ln_loss_b[0] * W0[400 * 256 + n];
    }
}

// ---------------- input LN staging: 8 threads per row, 32 rows ----------------
template<int L>
__device__ __forceinline__ void stage8(
    const float* __restrict__ src,
    const float* __restrict__ sc, const float* __restrict__ bi,
    unsigned short* xb, int dstcol, int tid, int row0)
{
    constexpr int SPAN = L / 8;
    const int sub = tid & 7;
    const int r   = tid >> 3;                  // 0..31
    const float* p = src + (size_t)(row0 + r) * L + sub * SPAN;
    float ps = 0.f, pq = 0.f;
    if constexpr (SPAN % 4 == 0) {
        constexpr int NV = SPAN / 4;
        float4 v[NV];
        #pragma unroll
        for (int j = 0; j < NV; ++j) {
            v[j] = *reinterpret_cast<const float4*>(p + 4 * j);
            ps += v[j].x + v[j].y + v[j].z + v[j].w;
            pq += v[j].x * v[j].x + v[j].y * v[j].y + v[j].z * v[j].z + v[j].w * v[j].w;
        }
        ps += __shfl_xor(ps, 1); ps += __shfl_xor(ps, 2); ps += __shfl_xor(ps, 4);
        pq += __shfl_xor(pq, 1); pq += __shfl_xor(pq, 2); pq += __shfl_xor(pq, 4);
        const float mu   = ps * (1.f / L);
        const float rstd = rsqrtf(pq * (1.f / L) - mu * mu + EPSV);
        unsigned short* dst = xb + r * XSTR + dstcol + sub * SPAN;
        const float* scp = sc + sub * SPAN;
        const float* bip = bi + sub * SPAN;
        #pragma unroll
        for (int j = 0; j < NV; ++j) {
            float4 sv = *reinterpret_cast<const float4*>(scp + 4 * j);
            float4 bv = *reinterpret_cast<const float4*>(bip + 4 * j);
            us4 o;
            o[0] = f2bf((v[j].x - mu) * rstd * sv.x + bv.x);
            o[1] = f2bf((v[j].y - mu) * rstd * sv.y + bv.y);
            o[2] = f2bf((v[j].z - mu) * rstd * sv.z + bv.z);
            o[3] = f2bf((v[j].w - mu) * rstd * sv.w + bv.w);
            *reinterpret_cast<us4*>(dst + 4 * j) = o;
        }
    } else {
        constexpr int NV = SPAN / 2;
        float2 v[NV];
        #pragma unroll
        for (int j = 0; j < NV; ++j) {
            v[j] = *reinterpret_cast<const float2*>(p + 2 * j);
            ps += v[j].x + v[j].y;
            pq += v[j].x * v[j].x + v[j].y * v[j].y;
        }
        ps += __shfl_xor(ps, 1); ps += __shfl_xor(ps, 2); ps += __shfl_xor(ps, 4);
        pq += __shfl_xor(pq, 1); pq += __shfl_xor(pq, 2); pq += __shfl_xor(pq, 4);
        const float mu   = ps * (1.f / L);
        const float rstd = rsqrtf(pq * (1.f / L) - mu * mu + EPSV);
        unsigned short* dst = xb + r * XSTR + dstcol + sub * SPAN;
        const float* scp = sc + sub * SPAN;
        const float* bip = bi + sub * SPAN;
        #pragma unroll
        for (int j = 0; j < NV; ++j) {
            float2 sv = *reinterpret_cast<const float2*>(scp + 2 * j);
            float2 bv = *reinterpret_cast<const float2*>(bip + 2 * j);
            unsigned int pk = (unsigned int)f2bf((v[j].x - mu) * rstd * sv.x + bv.x)
                            | ((unsigned int)f2bf((v[j].y - mu) * rstd * sv.y + bv.y) << 16);
            *reinterpret_cast<unsigned int*>(dst + 2 * j) = pk;
        }
    }
}

// ---------------- fused main kernel ----------------
// BM=32, 4 waves. All staging up front (no accumulator live during staging,
// R6 fix). GEMM3 uses fully-static per-branch unrolled loops — rule #20:
// runtime-bounded loops over ext_vector arrays go to scratch (R6's 97MB
// excess WRITE_SIZE).
// LDS lifecycle: x full (544) -> h0 (256, overwrites) -> h1 -> delta f32 (144)
__global__ __launch_bounds__(256, 4) void node_update_kernel(
    const float* __restrict__ logits, const float* __restrict__ hidden,
    const float* __restrict__ layer_pe, const float* __restrict__ intra,
    const int* __restrict__ layer, const float* __restrict__ msg,
    const float* __restrict__ ln_logits_s, const float* __restrict__ ln_logits_b,
    const float* __restrict__ ln_hidden_s, const float* __restrict__ ln_hidden_b,
    const float* __restrict__ ln_layer_pe_s, const float* __restrict__ ln_layer_pe_b,
    const float* __restrict__ ln_intra_pe_s, const float* __restrict__ ln_intra_pe_b,
    const float* __restrict__ ln_msg_s, const float* __restrict__ ln_msg_b,
    const unsigned short* __restrict__ W0p, const float* __restrict__ b0e,
    const float* __restrict__ mlp_ln0_s, const float* __restrict__ mlp_ln0_b,
    const unsigned short* __restrict__ W1p, const float* __restrict__ b1,
    const float* __restrict__ mlp_ln1_s, const float* __restrict__ mlp_ln1_b,
    const unsigned short* __restrict__ W2p, const float* __restrict__ b2,
    float* __restrict__ out)
{
    __shared__ __align__(16) unsigned short sbuf[BM * XSTR];  // 35328 B, multi-purpose
    __shared__ __align__(16) float redf[BM * 4 * 2];          // 1024 B
    __shared__ int lyr[BM];

    float2* redp = reinterpret_cast<float2*>(redf);
    const int tid  = threadIdx.x;
    const int lane = tid & 63;
    const int w    = tid >> 6;
    const int l15  = lane & 15;
    const int lg   = lane >> 4;
    const int row0 = blockIdx.x * BM;

    // ---- phase A: stage ALL 544 cols (no accumulator live) ----
    stage8<16 >(logits,   ln_logits_s,   ln_logits_b,   sbuf,   0, tid, row0);
    __builtin_amdgcn_sched_barrier(0);
    stage8<128>(hidden,   ln_hidden_s,   ln_hidden_b,   sbuf,  16, tid, row0);
    __builtin_amdgcn_sched_barrier(0);
    stage8<144>(msg,      ln_msg_s,      ln_msg_b,      sbuf, 144, tid, row0);
    __builtin_amdgcn_sched_barrier(0);
    stage8<128>(layer_pe, ln_layer_pe_s, ln_layer_pe_b, sbuf, 288, tid, row0);
    __builtin_amdgcn_sched_barrier(0);
    stage8<128>(intra,    ln_intra_pe_s, ln_intra_pe_b, sbuf, 416, tid, row0);
    __builtin_amdgcn_sched_barrier(0);
    if (tid < BM) lyr[tid] = layer[row0 + tid];
    __syncthreads();

    // ---- GEMM1 (K=544 in one loop), wave w owns cols 64w..64w+63, rows 0..31 ----
    f32x4 acc[2][4];
    #pragma unroll
    for (int m = 0; m < 2; ++m)
        #pragma unroll
        for (int t = 0; t < 4; ++t)
            acc[m][t] = (f32x4){0.f, 0.f, 0.f, 0.f};

    for (int s = 0; s < 17; ++s) {
        bf16x8 a[2];
        #pragma unroll
        for (int m = 0; m < 2; ++m)
            a[m] = *reinterpret_cast<const bf16x8*>(&sbuf[(16 * m + l15) * XSTR + 32 * s + 8 * lg]);
        #pragma unroll
        for (int t = 0; t < 4; ++t) {
            bf16x8 b = *reinterpret_cast<const bf16x8*>(W0p + (((s * 16 + w * 4 + t) * 64 + lane) << 3));
            #pragma unroll
            for (int m = 0; m < 2; ++m)
                acc[m][t] = __builtin_amdgcn_mfma_f32_16x16x32_bf16(a[m], b, acc[m][t], 0, 0, 0);
        }
    }

    // ---- LN0 + ReLU -> h0 (bf16, overwrites x in sbuf after barrier) ----
    {
        float bv[4], sv[4], bb[4];
        #pragma unroll
        for (int t = 0; t < 4; ++t) {
            int n = w * 64 + t * 16 + l15;
            bv[t] = b0e[n]; sv[t] = mlp_ln0_s[n]; bb[t] = mlp_ln0_b[n];
        }
        #pragma unroll
        for (int m = 0; m < 2; ++m)
            #pragma unroll
            for (int t = 0; t < 4; ++t)
                #pragma unroll
                for (int i = 0; i < 4; ++i)
                    acc[m][t][i] += bv[t];
        #pragma unroll
        for (int m = 0; m < 2; ++m) {
            #pragma unroll
            for (int i = 0; i < 4; ++i) {
                float ps = acc[m][0][i] + acc[m][1][i] + acc[m][2][i] + acc[m][3][i];
                float pq = acc[m][0][i] * acc[m][0][i] + acc[m][1][i] * acc[m][1][i]
                         + acc[m][2][i] * acc[m][2][i] + acc[m][3][i] * acc[m][3][i];
                ps += __shfl_xor(ps, 1); ps += __shfl_xor(ps, 2); ps += __shfl_xor(ps, 4); ps += __shfl_xor(ps, 8);
                pq += __shfl_xor(pq, 1); pq += __shfl_xor(pq, 2); pq += __shfl_xor(pq, 4); pq += __shfl_xor(pq, 8);
                if (l15 == 0) redp[(16 * m + 4 * lg + i) * 4 + w] = make_float2(ps, pq);
            }
        }
        __syncthreads();   // all GEMM1 LDS reads complete before h0 overwrite
        if (tid < BM) {
            float2 a0 = redp[tid * 4 + 0], a1 = redp[tid * 4 + 1], a2 = redp[tid * 4 + 2], a3 = redp[tid * 4 + 3];
            float s  = a0.x + a1.x + a2.x + a3.x;
            float q  = a0.y + a1.y + a2.y + a3.y;
            float mu = s * (1.f / 256.f);
            float rstd = rsqrtf(q * (1.f / 256.f) - mu * mu + EPSV);
            redp[tid * 4 + 0] = make_float2(mu, rstd);
        }
        __syncthreads();
        #pragma unroll
        for (int m = 0; m < 2; ++m)
            #pragma unroll
            for (int i = 0; i < 4; ++i) {
                int r = 16 * m + 4 * lg + i;
                float2 mr = redp[r * 4];
                #pragma unroll
                for (int t = 0; t < 4; ++t) {
                    float y = (acc[m][t][i] - mr.x) * mr.y * sv[t] + bb[t];
                    sbuf[r * XSTR + w * 64 + t * 16 + l15] = f2bf(fmaxf(y, 0.f));
                }
            }
    }
    __syncthreads();

    // ---- GEMM2 (256x256) reading h0 from sbuf ----
    #pragma unroll
    for (int m = 0; m < 2; ++m)
        #pragma unroll
        for (int t = 0; t < 4; ++t)
            acc[m][t] = (f32x4){0.f, 0.f, 0.f, 0.f};
    for (int s = 0; s < 8; ++s) {
        bf16x8 a[2];
        #pragma unroll
        for (int m = 0; m < 2; ++m)
            a[m] = *reinterpret_cast<const bf16x8*>(&sbuf[(16 * m + l15) * XSTR + 32 * s + 8 * lg]);
        #pragma unroll
        for (int t = 0; t < 4; ++t) {
            bf16x8 b = *reinterpret_cast<const bf16x8*>(W1p + (((s * 16 + w * 4 + t) * 64 + lane) << 3));
            #pragma unroll
            for (int m = 0; m < 2; ++m)
                acc[m][t] = __builtin_amdgcn_mfma_f32_16x16x32_bf16(a[m], b, acc[m][t], 0, 0, 0);
        }
    }

    // ---- LN1 + ReLU -> h1 (overwrites h0 in sbuf after barrier) ----
    {
        float bv[4], sv[4], bb[4];
        #pragma unroll
        for (int t = 0; t < 4; ++t) {
            int n = w * 64 + t * 16 + l15;
            bv[t] = b1[n]; sv[t] = mlp_ln1_s[n]; bb[t] = mlp_ln1_b[n];
        }
        #pragma unroll
        for (int m = 0; m < 2; ++m)
            #pragma unroll
            for (int t = 0; t < 4; ++t)
                #pragma unroll
                for (int i = 0; i < 4; ++i)
                    acc[m][t][i] += bv[t];
        #pragma unroll
        for (int m = 0; m < 2; ++m) {
            #pragma unroll
            for (int i = 0; i < 4; ++i) {
                float ps = acc[m][0][i] + acc[m][1][i] + acc[m][2][i] + acc[m][3][i];
                float pq = acc[m][0][i] * acc[m][0][i] + acc[m][1][i] * acc[m][1][i]
                         + acc[m][2][i] * acc[m][2][i] + acc[m][3][i] * acc[m][3][i];
                ps += __shfl_xor(ps, 1); ps += __shfl_xor(ps, 2); ps += __shfl_xor(ps, 4); ps += __shfl_xor(ps, 8);
                pq += __shfl_xor(pq, 1); pq += __shfl_xor(pq, 2); pq += __shfl_xor(pq, 4); pq += __shfl_xor(pq, 8);
                if (l15 == 0) redp[(16 * m + 4 * lg + i) * 4 + w] = make_float2(ps, pq);
            }
        }
        __syncthreads();   // all GEMM2 LDS reads complete
        if (tid < BM) {
            float2 a0 = redp[tid * 4 + 0], a1 = redp[tid * 4 + 1], a2 = redp[tid * 4 + 2], a3 = redp[tid * 4 + 3];
            float s  = a0.x + a1.x + a2.x + a3.x;
            float q  = a0.y + a1.y + a2.y + a3.y;
            float mu = s * (1.f / 256.f);
            float rstd = rsqrtf(q * (1.f / 256.f) - mu * mu + EPSV);
            redp[tid * 4 + 0] = make_float2(mu, rstd);
        }
        __syncthreads();
        #pragma unroll
        for (int m = 0; m < 2; ++m)
            #pragma unroll
            for (int i = 0; i < 4; ++i) {
                int r = 16 * m + 4 * lg + i;
                float2 mr = redp[r * 4];
                #pragma unroll
                for (int t = 0; t < 4; ++t) {
                    float y = (acc[m][t][i] - mr.x) * mr.y * sv[t] + bb[t];
                    sbuf[r * XSTR + w * 64 + t * 16 + l15] = f2bf(fmaxf(y, 0.f));
                }
            }
    }
    __syncthreads();

    // ---- GEMM3 (32x256 @ 256x144): wave w -> rows 16*(w&1).., col-half (w>>1) ----
    // Fully-static per-branch loops (rule #20: no runtime-bounded indexing of acc3)
    {
        const int rg = w & 1;            // row group: 0 -> rows 0..15, 1 -> rows 16..31
        const int ch = w >> 1;           // col half : 0 -> t 0..4,     1 -> t 5..8
        const unsigned short* arow = sbuf + (16 * rg + l15) * XSTR;
        float* delta = reinterpret_cast<float*>(sbuf);
        if (ch == 0) {
            f32x4 acc3[5];
            #pragma unroll
            for (int t = 0; t < 5; ++t) acc3[t] = (f32x4){0.f, 0.f, 0.f, 0.f};
            for (int s = 0; s < 8; ++s) {
                bf16x8 a = *reinterpret_cast<const bf16x8*>(arow + 32 * s + 8 * lg);
                #pragma unroll
                for (int t = 0; t < 5; ++t) {
                    bf16x8 b = *reinterpret_cast<const bf16x8*>(W2p + (((s * 9 + t) * 64 + lane) << 3));
                    acc3[t] = __builtin_amdgcn_mfma_f32_16x16x32_bf16(a, b, acc3[t], 0, 0, 0);
                }
            }
            __syncthreads();   // all h1 LDS reads done before delta overwrite
            #pragma unroll
            for (int t = 0; t < 5; ++t)
                #pragma unroll
                for (int i = 0; i < 4; ++i)
                    delta[(16 * rg + 4 * lg + i) * DSTR + 16 * t + l15] = acc3[t][i];
        } else {
            f32x4 acc3[4];
            #pragma unroll
            for (int t = 0; t < 4; ++t) acc3[t] = (f32x4){0.f, 0.f, 0.f, 0.f};
            for (int s = 0; s < 8; ++s) {
                bf16x8 a = *reinterpret_cast<const bf16x8*>(arow + 32 * s + 8 * lg);
                #pragma unroll
                for (int t = 0; t < 4; ++t) {
                    bf16x8 b = *reinterpret_cast<const bf16x8*>(W2p + (((s * 9 + t + 5) * 64 + lane) << 3));
                    acc3[t] = __builtin_amdgcn_mfma_f32_16x16x32_bf16(a, b, acc3[t], 0, 0, 0);
                }
            }
            __syncthreads();   // matches the ch==0 barrier (uniform per block)
            #pragma unroll
            for (int t = 0; t < 4; ++t)
                #pragma unroll
                for (int i = 0; i < 4; ++i)
                    delta[(16 * rg + 4 * lg + i) * DSTR + 16 * (t + 5) + l15] = acc3[t][i];
        }
    }
    __syncthreads();

    // ---- epilogue: out = mask ? base + delta + b2 : base ----
    const float* delta = reinterpret_cast<const float*>(sbuf);
    #pragma unroll
    for (int j = 0; j < 5; ++j) {
        int idx = tid + j * 256;          // 0..1151 ; 36 float4 per row, 32 rows
        if (idx < BM * 36) {
            int r = idx / 36, c4 = idx % 36;
            int grow = row0 + r;
            float4 d  = *reinterpret_cast<const float4*>(delta + r * DSTR + 4 * c4);
            float4 bb = *reinterpret_cast<const float4*>(b2 + 4 * c4);
            float4 base;
            if (c4 < 4) base = *reinterpret_cast<const float4*>(logits + (size_t)grow * 16 + 4 * c4);
            else        base = *reinterpret_cast<const float4*>(hidden + (size_t)grow * 128 + 4 * c4 - 16);
            const bool mk = lyr[r] > 0;
            float4 o;
            o.x = mk ? base.x + d.x + bb.x : base.x;
            o.y = mk ? base.y + d.y + bb.y : base.y;
            o.z = mk ? base.z + d.z + bb.z : base.z;
            o.w = mk ? base.w + d.w + bb.w : base.w;
            *reinterpret_cast<float4*>(out + (size_t)grow * 144 + 4 * c4) = o;
        }
    }
}

extern "C" void kernel_launch(void* const* d_in, const int* in_sizes, int n_in,
                              void* d_out, int out_size, void* d_ws, size_t ws_size,
                              hipStream_t stream)
{
    const float* logits        = (const float*)d_in[0];
    const float* hidden        = (const float*)d_in[1];
    const float* layer_pe      = (const float*)d_in[2];
    const float* intra         = (const float*)d_in[3];
    // d_in[4] = loss: unused (LN of a scalar == its bias)
    const int*   layer         = (const int*)  d_in[5];
    const float* msg           = (const float*)d_in[6];
    const float* ln_logits_s   = (const float*)d_in[7];
    const float* ln_logits_b   = (const float*)d_in[8];
    const float* ln_hidden_s   = (const float*)d_in[9];
    const float* ln_hidden_b   = (const float*)d_in[10];
    const float* ln_layer_pe_s = (const float*)d_in[11];
    const float* ln_layer_pe_b = (const float*)d_in[12];
    const float* ln_intra_pe_s = (const float*)d_in[13];
    const float* ln_intra_pe_b = (const float*)d_in[14];
    // d_in[15] = ln_loss_s: unused
    const float* ln_loss_b     = (const float*)d_in[16];
    const float* ln_msg_s      = (const float*)d_in[17];
    const float* ln_msg_b      = (const float*)d_in[18];
    const float* W0            = (const float*)d_in[19];
    const float* b0            = (const float*)d_in[20];
    const float* mlp_ln0_s     = (const float*)d_in[21];
    const float* mlp_ln0_b     = (const float*)d_in[22];
    const float* W1            = (const float*)d_in[23];
    const float* b1            = (const float*)d_in[24];
    const float* mlp_ln1_s     = (const float*)d_in[25];
    const float* mlp_ln1_b     = (const float*)d_in[26];
    const float* W2            = (const float*)d_in[27];
    const float* b2            = (const float*)d_in[28];
    float* out = (float*)d_out;

    // workspace layout (485 KB): W0p | W1p | W2p | b0_eff
    unsigned short* W0p = (unsigned short*)d_ws;                     // 278528 B
    unsigned short* W1p = (unsigned short*)((char*)d_ws + 278528);   // 131072 B
    unsigned short* W2p = (unsigned short*)((char*)d_ws + 409600);   //  73728 B
    float*          b0e = (float*)((char*)d_ws + 483328);            //   1024 B

    prep_kernel<<<119, 256, 0, stream>>>(W0, b0, ln_loss_b, W1, W2, W0p, W1p, W2p, b0e);

    const int N = in_sizes[5];               // 200000, divisible by BM=32
    node_update_kernel<<<N / BM, 256, 0, stream>>>(
        logits, hidden, layer_pe, intra, layer, msg,
        ln_logits_s, ln_logits_b, ln_hidden_s, ln_hidden_b,
        ln_layer_pe_s, ln_layer_pe_b, ln_intra_pe_s, ln_intra_pe_b,
        ln_msg_s, ln_msg_b,
        W0p, b0e, mlp_ln0_s, mlp_ln0_b,
        W1p, b1, mlp_ln1_s, mlp_ln1_b,
        W2p, b2, out);
}